// Round 4
// baseline (806.597 us; speedup 1.0000x reference)
//
#include <hip/hip_runtime.h>
#include <hip/hip_bf16.h>

#define BQ 16      // batches
#define NG 64      // groups
#define SQ 4096    // sequence tokens
#define CD 768     // channels
#define ROWS (BQ*NG)
#define KSP 4      // split-K factor (768 = 4 * 192)

// ---------------------------------------------------------------------------
// transpose64: dst[N x M] = src[M x N]^T, 64x64 LDS tiles
// ---------------------------------------------------------------------------
__global__ __launch_bounds__(256)
void transpose64(const float* __restrict__ src, float* __restrict__ dst,
                 int M, int N)
{
    __shared__ float t[64][65];
    const int bx = blockIdx.x * 64;
    const int by = blockIdx.y * 64;
    const int tx = threadIdx.x & 63, tw = threadIdx.x >> 6;
#pragma unroll
    for (int i = 0; i < 16; ++i) {
        const int row = i * 4 + tw;
        t[row][tx] = src[(size_t)(by + row) * N + bx + tx];
    }
    __syncthreads();
#pragma unroll
    for (int i = 0; i < 16; ++i) {
        const int row = i * 4 + tw;
        dst[(size_t)(bx + row) * M + by + tx] = t[tx][row];
    }
}

// ---------------------------------------------------------------------------
// vecmat3: three fused vec@mat precomputes (blockIdx.y selects)
//   y=0: uq  = Wq^T bk      y=1: bqk = bq @ Wk      y=2: bvo = bv @ Wo^T
// ---------------------------------------------------------------------------
__global__ __launch_bounds__(256)
void vecmat3(const float* __restrict__ Wq, const float* __restrict__ bk,
             const float* __restrict__ Wk, const float* __restrict__ bq,
             const float* __restrict__ WoT, const float* __restrict__ bv,
             float* __restrict__ uq, float* __restrict__ bqk,
             float* __restrict__ bvo)
{
    __shared__ float red[4][64];
    const float* Mm; const float* v; float* out;
    if (blockIdx.y == 0)      { Mm = Wq;  v = bk; out = uq;  }
    else if (blockIdx.y == 1) { Mm = Wk;  v = bq; out = bqk; }
    else                      { Mm = WoT; v = bv; out = bvo; }
    const int j0 = blockIdx.x * 64;
    const int jl = threadIdx.x & 63;
    const int cs = threadIdx.x >> 6;
    double a = 0.0;
    for (int c = cs; c < CD; c += 4)
        a += (double)Mm[(size_t)c * CD + j0 + jl] * (double)v[c];
    red[cs][jl] = (float)a;
    __syncthreads();
    if (cs == 0) out[j0 + jl] = red[0][jl] + red[1][jl] + red[2][jl] + red[3][jl];
}

// ---------------------------------------------------------------------------
// delta_q: delta[r] = query[r,:].uq + bq.bk  (fp64)
// ---------------------------------------------------------------------------
__global__ __launch_bounds__(256)
void delta_q(const float* __restrict__ query, const float* __restrict__ uq,
             const float* __restrict__ bq, const float* __restrict__ bk,
             double* __restrict__ delta)
{
    const int r    = blockIdx.x * 4 + (threadIdx.x >> 6);
    const int lane = threadIdx.x & 63;
    double a = 0.0, b = 0.0;
    for (int c = lane; c < CD; c += 64) {
        a += (double)query[(size_t)r * CD + c] * (double)uq[c];
        b += (double)bq[c] * (double)bk[c];
    }
    a += b;
    for (int off = 32; off; off >>= 1) a += __shfl_down(a, off, 64);
    if (lane == 0) delta[r] = a;
}

// ---------------------------------------------------------------------------
// gemm_core: 256-thread 64x64 tile, K=192 per call (3 chunks of 64),
// 4x4 per lane. AT is A TRANSPOSED [768][lda] (staging = direct copy).
// LDS pad 72 -> all fragment reads and staging stores <=2-way (free).
// fp32 per-64-chunk partials folded into fp64 (proven score-path recipe).
// Writes fp32 partial tile into Pz (row stride CD).
// ---------------------------------------------------------------------------
__device__ __forceinline__
void gemm_core(const float* __restrict__ AT, int lda,
               const float* __restrict__ B,  int ldb,
               float* __restrict__ Pz, int r0, int c0, int k0, int prow0)
{
    __shared__ float As[64][72];
    __shared__ float Bs[64][72];
    const int tid = threadIdx.x;
    const int c4  = tid & 15;     // staging float4 col
    const int kr  = tid >> 4;     // staging row step
    const int cg  = tid & 15;     // output col group
    const int rg  = tid >> 4;     // output row group

    float  acc[4][4]; double acc64[4][4];
#pragma unroll
    for (int i = 0; i < 4; ++i)
#pragma unroll
        for (int j = 0; j < 4; ++j) { acc[i][j] = 0.f; acc64[i][j] = 0.0; }

    for (int ch = 0; ch < 3; ++ch) {
        const int kb = k0 + ch * 64;
        if (ch) __syncthreads();
#pragma unroll
        for (int i = 0; i < 4; ++i) {
            const int row = i * 16 + kr;
            *(float4*)&As[row][4 * c4] = *(const float4*)(AT + (size_t)(kb + row) * lda + r0 + 4 * c4);
            *(float4*)&Bs[row][4 * c4] = *(const float4*)(B  + (size_t)(kb + row) * ldb + c0 + 4 * c4);
        }
        __syncthreads();
#pragma unroll 8
        for (int dd = 0; dd < 64; ++dd) {
            const float4 a = *(const float4*)&As[dd][4 * rg];
            const float4 b = *(const float4*)&Bs[dd][4 * cg];
            const float av[4] = {a.x, a.y, a.z, a.w};
            const float bv[4] = {b.x, b.y, b.z, b.w};
#pragma unroll
            for (int i = 0; i < 4; ++i)
#pragma unroll
                for (int j = 0; j < 4; ++j) acc[i][j] += av[i] * bv[j];
        }
#pragma unroll
        for (int i = 0; i < 4; ++i)
#pragma unroll
            for (int j = 0; j < 4; ++j) { acc64[i][j] += (double)acc[i][j]; acc[i][j] = 0.f; }
    }
#pragma unroll
    for (int i = 0; i < 4; ++i) {
        const int row = prow0 + 4 * rg + i;
        float4 v;
        v.x = (float)acc64[i][0]; v.y = (float)acc64[i][1];
        v.z = (float)acc64[i][2]; v.w = (float)acc64[i][3];
        *(float4*)(Pz + (size_t)row * CD + c0 + 4 * cg) = v;
    }
}

// weight GEMMs fused: by<12 -> Wqk = Wq^T@Wk; by>=12 -> Wvo = Wv^T@Wo^T
__global__ __launch_bounds__(256)
void gemm_w(const float* __restrict__ Wq, const float* __restrict__ Wk,
            const float* __restrict__ Wv, const float* __restrict__ WoT,
            float* __restrict__ P)
{
    const int by = blockIdx.y;
    float* Pz = P + (size_t)blockIdx.z * (1536 * CD);
    const float* AT; const float* Bp; int r0;
    if (by < 12) { AT = Wq; Bp = Wk;  r0 = by * 64; }
    else         { AT = Wv; Bp = WoT; r0 = (by - 12) * 64; }
    gemm_core(AT, CD, Bp, CD, Pz, r0, blockIdx.x * 64, blockIdx.z * 192, by * 64);
}

// data GEMM: out-rows M=1024, AT [768][1024]
__global__ __launch_bounds__(256)
void gemm_d(const float* __restrict__ AT, const float* __restrict__ B,
            float* __restrict__ P)
{
    float* Pz = P + (size_t)blockIdx.z * (ROWS * CD);
    const int r0 = blockIdx.y * 64;
    gemm_core(AT, ROWS, B, CD, Pz, r0, blockIdx.x * 64, blockIdx.z * 192, r0);
}

// ---------------------------------------------------------------------------
// reduce_sk: out[e] = fp64 sum of KSP partials (+ epilogue).
// mode 0: none; 1: +bias[c]; 3: invf*acc + bsc*bias2[c] + bias[c]
// ---------------------------------------------------------------------------
__global__ __launch_bounds__(256)
void reduce_sk(const float* __restrict__ P, const float* __restrict__ bias,
               const float* __restrict__ bias2, const int* __restrict__ cnt,
               float* __restrict__ out, int M, int mode)
{
    const int e = blockIdx.x * 256 + threadIdx.x;
    if (e >= M * CD) return;
    const size_t MN = (size_t)M * CD;
    double a = 0.0;
#pragma unroll
    for (int z = 0; z < KSP; ++z) a += (double)P[z * MN + e];
    float v = (float)a;
    if (mode == 1) v += bias[e % CD];
    else if (mode == 3) {
        const int r = e / CD;
        const int cv = cnt[r];
        const float invf = 1.f / ((float)cv + 1.f);   // ASSIGN_EPS = 1
        v = v * invf + ((float)cv * invf) * bias2[e % CD] + bias[e % CD];
    }
    out[e] = v;
}

// ---------------------------------------------------------------------------
// score_argmax v5: register-resident g, scalar-pipe key, NO LDS in the
// inner loop.
//   * Block = 12 waves (768 thr). Wave w owns k-chunk [64w, 64w+64);
//     lane l = group n. greg[64] holds g[b][n=l][64w..64w+64) (VGPRs),
//     loaded coalesced from gT once per block.
//   * key[s][64w..64w+64) is WAVE-UNIFORM -> scalar loads (SGPRs).
//     Inner loop per s: 64 x v_fmac_f32 acc, s_key, v_greg. Zero LDS/VMEM.
//   * Chunk partials -> LDS (64 consecutive dwords per wave, conflict-free),
//     folded to fp64 in ASCENDING chunk order t=0..11 (proven fold), +delta
//     (fp64), strict-> / ascending-n argmax.
// Numerics BIT-IDENTICAL to the proven kernel: per (n,s) one fp32 FMA chain
// per 64-chunk ascending k (same `a += g*k` contraction), fp64 fold at the
// same 12 boundaries in the same order, same delta add, same tie-break.
// ---------------------------------------------------------------------------
#define STILE 256   // s-range per block
#define SB    16    // s-batch between barriers

__global__ __launch_bounds__(768)
void score_argmax(const float* __restrict__ gT, const float* __restrict__ key,
                  const double* __restrict__ delta, int* __restrict__ idxo)
{
    __shared__ float  part[SB][12][64];   // 48 KB
    __shared__ double sc[SB][65];         // 8.1 KB (pad 65 -> argmax reads spread banks)
    __shared__ double dl[64];

    const int tid = threadIdx.x;
    const int b   = blockIdx.y;
    const int s0  = blockIdx.x * STILE;
    const int w   = __builtin_amdgcn_readfirstlane(tid >> 6);  // chunk id 0..11 (uniform)
    const int l   = tid & 63;                                   // n

    if (tid < 64) dl[tid] = delta[b * 64 + tid];

    // g-slice into registers: greg[kk] = g[b][n=l][k=64w+kk] (coalesced from gT)
    float greg[64];
#pragma unroll
    for (int kk = 0; kk < 64; ++kk)
        greg[kk] = gT[(size_t)(w * 64 + kk) * ROWS + b * 64 + l];

    const float* keyb = key + (size_t)b * SQ * CD + (size_t)w * 64;

    __syncthreads();   // dl ready

    for (int sb = 0; sb < STILE; sb += SB) {
        // ---- compute: fp32 chunk partial per (s, n=lane), ascending-k chain
        for (int si = 0; si < SB; ++si) {
            const float* kp = keyb + (size_t)(s0 + sb + si) * CD;   // wave-uniform
            float a = 0.f;
#pragma unroll
            for (int q = 0; q < 16; ++q) {
                const float4 kv = *(const float4*)(kp + 4 * q);
                a += greg[4 * q + 0] * kv.x;
                a += greg[4 * q + 1] * kv.y;
                a += greg[4 * q + 2] * kv.z;
                a += greg[4 * q + 3] * kv.w;
            }
            part[si][w][l] = a;      // 64 consecutive dwords per wave
        }
        __syncthreads();
        // ---- fold: fp64 sum of chunks in ASCENDING t order + delta
        for (int si = w; si < SB; si += 12) {
            double acc = 0.0;
#pragma unroll
            for (int t = 0; t < 12; ++t) acc += (double)part[si][t][l];
            sc[si][l] = acc + dl[l];
        }
        __syncthreads();
        // ---- argmax over n (strict >, ascending n)
        if (tid < SB) {
            double best = sc[tid][0]; int bi = 0;
            for (int n = 1; n < 64; ++n) {
                const double v = sc[tid][n];
                if (v > best) { best = v; bi = n; }
            }
            idxo[b * SQ + s0 + sb + tid] = bi;
        }
        __syncthreads();
    }
}

// ---------------------------------------------------------------------------
// gather_ksum (proven R3 kernel)
// ---------------------------------------------------------------------------
__global__ __launch_bounds__(256)
void gather_ksum(const float* __restrict__ key, const int* __restrict__ idx,
                 float* __restrict__ Ksum, int* __restrict__ cnt)
{
    __shared__ int slist[SQ];
    __shared__ int scount;
    const int n   = blockIdx.x;
    const int b   = blockIdx.y;
    const int tid = threadIdx.x;
    if (tid == 0) scount = 0;
    __syncthreads();

    const int* ib = idx + b * SQ;
#pragma unroll
    for (int p = 0; p < SQ / 256; ++p) {
        const int s = p * 256 + tid;
        if (ib[s] == n) {
            const int pos = atomicAdd(&scount, 1);
            slist[pos] = s;
        }
    }
    __syncthreads();
    const int m = scount;

    double a0 = 0.0, a1 = 0.0, a2 = 0.0;
    const float* kb = key + (size_t)b * SQ * CD;
    const int c1 = tid + 256, c2 = tid + 512;

    int r = 0;
    for (; r + 4 <= m; r += 4) {
        const float* p0 = kb + (size_t)slist[r]     * CD;
        const float* p1 = kb + (size_t)slist[r + 1] * CD;
        const float* p2 = kb + (size_t)slist[r + 2] * CD;
        const float* p3 = kb + (size_t)slist[r + 3] * CD;
        a0 += (double)p0[tid] + (double)p1[tid] + (double)p2[tid] + (double)p3[tid];
        a1 += (double)p0[c1] + (double)p1[c1] + (double)p2[c1] + (double)p3[c1];
        a2 += (double)p0[c2] + (double)p1[c2] + (double)p2[c2] + (double)p3[c2];
    }
    for (; r < m; ++r) {
        const float* p0 = kb + (size_t)slist[r] * CD;
        a0 += (double)p0[tid]; a1 += (double)p0[c1]; a2 += (double)p0[c2];
    }

    float* out = Ksum + (size_t)(b * 64 + n) * CD;
    out[tid] = (float)a0; out[c1] = (float)a1; out[c2] = (float)a2;
    if (tid == 0) cnt[b * 64 + n] = m;
}

// ---------------------------------------------------------------------------
extern "C" void kernel_launch(void* const* d_in, const int* in_sizes, int n_in,
                              void* d_out, int out_size, void* d_ws, size_t ws_size,
                              hipStream_t stream)
{
    const float* query = (const float*)d_in[0];
    const float* key   = (const float*)d_in[1];
    const float* Wq    = (const float*)d_in[2];
    const float* bq    = (const float*)d_in[3];
    const float* Wk    = (const float*)d_in[4];
    const float* bk    = (const float*)d_in[5];
    const float* Wv    = (const float*)d_in[6];
    const float* bv    = (const float*)d_in[7];
    const float* Wo    = (const float*)d_in[8];
    const float* bo    = (const float*)d_in[9];

    char* ws = (char*)d_ws;
    const size_t MB = 1 << 20;
    int*    cnt   = (int*)   (ws + 0);               //   4 KB
    double* delta = (double*)(ws + 4096);            //   8 KB
    float*  uq    = (float*) (ws + 16384);           //   3 KB
    float*  bqk   = (float*) (ws + 19456);           //   3 KB
    float*  bvo   = (float*) (ws + 22528);           //   3 KB
    int*    idx   = (int*)   (ws + 32768);           // 256 KB
    float*  qT    = (float*) (ws + 1 * MB);          //   3 MB  [768][1024]
    float*  WoT   = (float*) (ws + 4 * MB);          // 2.25 MB [768][768]
    float*  Wqk   = (float*) (ws + 7 * MB);          // 2.25 MB (contiguous with Wvo)
    float*  Wvo   = Wqk + 768 * 768;                 // 2.25 MB
    float*  g     = (float*) (ws + 12 * MB);         //   3 MB  [1024][768]
    float*  Ksum  = (float*) (ws + 15 * MB);         //   3 MB
    float*  KsumT = (float*) (ws + 18 * MB);         //   3 MB  [768][1024]
    float*  P     = (float*) (ws + 21 * MB);         //  19 MB  partials

    // weight precomputes
    transpose64<<<dim3(12, 12), 256, 0, stream>>>(Wo, WoT, CD, CD);
    transpose64<<<dim3(12, 16), 256, 0, stream>>>(query, qT, ROWS, CD);
    vecmat3<<<dim3(12, 3), 256, 0, stream>>>(Wq, bk, Wk, bq, WoT, bv, uq, bqk, bvo);
    delta_q<<<ROWS / 4, 256, 0, stream>>>(query, uq, bq, bk, delta);
    // [Wqk ; Wvo] = [Wq^T@Wk ; Wv^T@Wo^T]
    gemm_w<<<dim3(12, 24, KSP), 256, 0, stream>>>(Wq, Wk, Wv, WoT, P);
    reduce_sk<<<(1536 * CD) / 256, 256, 0, stream>>>(P, nullptr, nullptr, nullptr, Wqk, 1536, 0);
    // g = query @ Wqk + bqk
    gemm_d<<<dim3(12, 16, KSP), 256, 0, stream>>>(qT, Wqk, P);
    reduce_sk<<<(ROWS * CD) / 256, 256, 0, stream>>>(P, bqk, nullptr, nullptr, g, ROWS, 1);
    // gT = g^T [768][1024] -- reuses qT space (qT is dead after the gemm above)
    float* gT = qT;
    transpose64<<<dim3(12, 16), 256, 0, stream>>>(g, gT, ROWS, CD);
    // argmax assignment (v5: 12 waves, g-in-registers, scalar-pipe key)
    score_argmax<<<dim3(SQ / STILE, BQ), 768, 0, stream>>>(gT, key, delta, idx);
    // Ksum / cnt
    gather_ksum<<<dim3(NG, BQ), 256, 0, stream>>>(key, idx, Ksum, cnt);
    transpose64<<<dim3(12, 16), 256, 0, stream>>>(Ksum, KsumT, ROWS, CD);
    // out = invf*(Ksum @ Wvo) + bsc*bvo + bo
    gemm_d<<<dim3(12, 16, KSP), 256, 0, stream>>>(KsumT, Wvo, P);
    reduce_sk<<<(ROWS * CD) / 256, 256, 0, stream>>>(P, bo, bvo, cnt, (float*)d_out, ROWS, 3);
}

// Round 5
// 700.359 us; speedup vs baseline: 1.1517x; 1.1517x over previous
//
#include <hip/hip_runtime.h>
#include <hip/hip_bf16.h>

#define BQ 16      // batches
#define NG 64      // groups
#define SQ 4096    // sequence tokens
#define CD 768     // channels
#define ROWS (BQ*NG)
#define KSP 4      // split-K factor (768 = 4 * 192)

// ---------------------------------------------------------------------------
// transpose64: dst[N x M] = src[M x N]^T, 64x64 LDS tiles
// ---------------------------------------------------------------------------
__global__ __launch_bounds__(256)
void transpose64(const float* __restrict__ src, float* __restrict__ dst,
                 int M, int N)
{
    __shared__ float t[64][65];
    const int bx = blockIdx.x * 64;
    const int by = blockIdx.y * 64;
    const int tx = threadIdx.x & 63, tw = threadIdx.x >> 6;
#pragma unroll
    for (int i = 0; i < 16; ++i) {
        const int row = i * 4 + tw;
        t[row][tx] = src[(size_t)(by + row) * N + bx + tx];
    }
    __syncthreads();
#pragma unroll
    for (int i = 0; i < 16; ++i) {
        const int row = i * 4 + tw;
        dst[(size_t)(bx + row) * M + by + tx] = t[tx][row];
    }
}

// ---------------------------------------------------------------------------
// vecmat3: three fused vec@mat precomputes (blockIdx.y selects)
//   y=0: uq  = Wq^T bk      y=1: bqk = bq @ Wk      y=2: bvo = bv @ Wo^T
// ---------------------------------------------------------------------------
__global__ __launch_bounds__(256)
void vecmat3(const float* __restrict__ Wq, const float* __restrict__ bk,
             const float* __restrict__ Wk, const float* __restrict__ bq,
             const float* __restrict__ WoT, const float* __restrict__ bv,
             float* __restrict__ uq, float* __restrict__ bqk,
             float* __restrict__ bvo)
{
    __shared__ float red[4][64];
    const float* Mm; const float* v; float* out;
    if (blockIdx.y == 0)      { Mm = Wq;  v = bk; out = uq;  }
    else if (blockIdx.y == 1) { Mm = Wk;  v = bq; out = bqk; }
    else                      { Mm = WoT; v = bv; out = bvo; }
    const int j0 = blockIdx.x * 64;
    const int jl = threadIdx.x & 63;
    const int cs = threadIdx.x >> 6;
    double a = 0.0;
    for (int c = cs; c < CD; c += 4)
        a += (double)Mm[(size_t)c * CD + j0 + jl] * (double)v[c];
    red[cs][jl] = (float)a;
    __syncthreads();
    if (cs == 0) out[j0 + jl] = red[0][jl] + red[1][jl] + red[2][jl] + red[3][jl];
}

// ---------------------------------------------------------------------------
// delta_q: delta[r] = query[r,:].uq + bq.bk  (fp64)
// ---------------------------------------------------------------------------
__global__ __launch_bounds__(256)
void delta_q(const float* __restrict__ query, const float* __restrict__ uq,
             const float* __restrict__ bq, const float* __restrict__ bk,
             double* __restrict__ delta)
{
    const int r    = blockIdx.x * 4 + (threadIdx.x >> 6);
    const int lane = threadIdx.x & 63;
    double a = 0.0, b = 0.0;
    for (int c = lane; c < CD; c += 64) {
        a += (double)query[(size_t)r * CD + c] * (double)uq[c];
        b += (double)bq[c] * (double)bk[c];
    }
    a += b;
    for (int off = 32; off; off >>= 1) a += __shfl_down(a, off, 64);
    if (lane == 0) delta[r] = a;
}

// ---------------------------------------------------------------------------
// gemm_core: 256-thread 64x64 tile, K=192 per call (3 chunks of 64),
// 4x4 per lane. AT is A TRANSPOSED [768][lda] (staging = direct copy).
// LDS pad 72 -> all fragment reads and staging stores <=2-way (free).
// fp32 per-64-chunk partials folded into fp64 (proven score-path recipe).
// Writes fp32 partial tile into Pz (row stride CD).
// ---------------------------------------------------------------------------
__device__ __forceinline__
void gemm_core(const float* __restrict__ AT, int lda,
               const float* __restrict__ B,  int ldb,
               float* __restrict__ Pz, int r0, int c0, int k0, int prow0)
{
    __shared__ float As[64][72];
    __shared__ float Bs[64][72];
    const int tid = threadIdx.x;
    const int c4  = tid & 15;     // staging float4 col
    const int kr  = tid >> 4;     // staging row step
    const int cg  = tid & 15;     // output col group
    const int rg  = tid >> 4;     // output row group

    float  acc[4][4]; double acc64[4][4];
#pragma unroll
    for (int i = 0; i < 4; ++i)
#pragma unroll
        for (int j = 0; j < 4; ++j) { acc[i][j] = 0.f; acc64[i][j] = 0.0; }

    for (int ch = 0; ch < 3; ++ch) {
        const int kb = k0 + ch * 64;
        if (ch) __syncthreads();
#pragma unroll
        for (int i = 0; i < 4; ++i) {
            const int row = i * 16 + kr;
            *(float4*)&As[row][4 * c4] = *(const float4*)(AT + (size_t)(kb + row) * lda + r0 + 4 * c4);
            *(float4*)&Bs[row][4 * c4] = *(const float4*)(B  + (size_t)(kb + row) * ldb + c0 + 4 * c4);
        }
        __syncthreads();
#pragma unroll 8
        for (int dd = 0; dd < 64; ++dd) {
            const float4 a = *(const float4*)&As[dd][4 * rg];
            const float4 b = *(const float4*)&Bs[dd][4 * cg];
            const float av[4] = {a.x, a.y, a.z, a.w};
            const float bv[4] = {b.x, b.y, b.z, b.w};
#pragma unroll
            for (int i = 0; i < 4; ++i)
#pragma unroll
                for (int j = 0; j < 4; ++j) acc[i][j] += av[i] * bv[j];
        }
#pragma unroll
        for (int i = 0; i < 4; ++i)
#pragma unroll
            for (int j = 0; j < 4; ++j) { acc64[i][j] += (double)acc[i][j]; acc[i][j] = 0.f; }
    }
#pragma unroll
    for (int i = 0; i < 4; ++i) {
        const int row = prow0 + 4 * rg + i;
        float4 v;
        v.x = (float)acc64[i][0]; v.y = (float)acc64[i][1];
        v.z = (float)acc64[i][2]; v.w = (float)acc64[i][3];
        *(float4*)(Pz + (size_t)row * CD + c0 + 4 * cg) = v;
    }
}

// weight GEMMs fused: by<12 -> Wqk = Wq^T@Wk; by>=12 -> Wvo = Wv^T@Wo^T
__global__ __launch_bounds__(256)
void gemm_w(const float* __restrict__ Wq, const float* __restrict__ Wk,
            const float* __restrict__ Wv, const float* __restrict__ WoT,
            float* __restrict__ P)
{
    const int by = blockIdx.y;
    float* Pz = P + (size_t)blockIdx.z * (1536 * CD);
    const float* AT; const float* Bp; int r0;
    if (by < 12) { AT = Wq; Bp = Wk;  r0 = by * 64; }
    else         { AT = Wv; Bp = WoT; r0 = (by - 12) * 64; }
    gemm_core(AT, CD, Bp, CD, Pz, r0, blockIdx.x * 64, blockIdx.z * 192, by * 64);
}

// data GEMM: out-rows M=1024, AT [768][1024]
__global__ __launch_bounds__(256)
void gemm_d(const float* __restrict__ AT, const float* __restrict__ B,
            float* __restrict__ P)
{
    float* Pz = P + (size_t)blockIdx.z * (ROWS * CD);
    const int r0 = blockIdx.y * 64;
    gemm_core(AT, ROWS, B, CD, Pz, r0, blockIdx.x * 64, blockIdx.z * 192, r0);
}

// ---------------------------------------------------------------------------
// reduce_sk: out[e] = fp64 sum of KSP partials (+ epilogue).
// mode 0: none; 1: +bias[c]; 3: invf*acc + bsc*bias2[c] + bias[c]
// ---------------------------------------------------------------------------
__global__ __launch_bounds__(256)
void reduce_sk(const float* __restrict__ P, const float* __restrict__ bias,
               const float* __restrict__ bias2, const int* __restrict__ cnt,
               float* __restrict__ out, int M, int mode)
{
    const int e = blockIdx.x * 256 + threadIdx.x;
    if (e >= M * CD) return;
    const size_t MN = (size_t)M * CD;
    double a = 0.0;
#pragma unroll
    for (int z = 0; z < KSP; ++z) a += (double)P[z * MN + e];
    float v = (float)a;
    if (mode == 1) v += bias[e % CD];
    else if (mode == 3) {
        const int r = e / CD;
        const int cv = cnt[r];
        const float invf = 1.f / ((float)cv + 1.f);   // ASSIGN_EPS = 1
        v = v * invf + ((float)cv * invf) * bias2[e % CD] + bias[e % CD];
    }
    out[e] = v;
}

// ---------------------------------------------------------------------------
// score_argmax v6: EXACT v1 structure/layout/compute (proven 161us), with
// ONLY the staging thread->element assignment changed to kill the 8-way
// staging-write bank conflicts (v1's 1.7e7 conflict cycles):
//   * each thread loads k = c4 + 16*i (4 scalar b32 loads, 64B-coalesced
//     per instruction) instead of a float4 at k = 4*c4..4*c4+3.
//   * kt write bank becomes 4*((gs+c4)&7)+lo -> 32 banks, 2 lanes each (free)
//   * gt write bank becomes (4*c4+16(p&1)+lrow)%32 -> 2-way (free)
// Every LDS element lands in the SAME slot as v1 -> compute phase and
// numerics BIT-IDENTICAL (ascending-dd fp32 chains, fp64 fold per 64-chunk,
// fp64 +delta, strict-> / ascending-n argmax).
// ---------------------------------------------------------------------------
struct ScoreTiles { float gt[64][68]; float ktA[64][64]; float ktB[64][64]; };
struct ScoreRed   { double bval[128][17]; int bidx[128][17]; };
union  ScoreShared { ScoreTiles t; ScoreRed r; };

__global__ __launch_bounds__(256)
void score_argmax(const float* __restrict__ g, const float* __restrict__ key,
                  const double* __restrict__ delta, int* __restrict__ idxo)
{
    __shared__ alignas(16) ScoreShared sh;
    __shared__ double dl[64];
    const int tid  = threadIdx.x;
    const int b    = blockIdx.y;
    const int s0   = blockIdx.x * 128;
    const int sg   = tid & 15;    // s = 8*sg + j
    const int ng   = tid >> 4;    // n = 4*ng + i
    const int lrow = tid >> 4;
    const int c4   = tid & 15;

    if (tid < 64) dl[tid] = delta[b * 64 + tid];

    float  accC[4][8];
    double acc64[4][8];
#pragma unroll
    for (int i = 0; i < 4; ++i)
#pragma unroll
        for (int j = 0; j < 8; ++j) { accC[i][j] = 0.f; acc64[i][j] = 0.0; }

    for (int kc = 0; kc < CD; kc += 64) {
        // stage g transposed: gt[k-local][n]; k = c4 + 16*i per thread
        // (b32 loads, 64B segments; write bank = (4*c4 + nrow)%32 -> 2-way)
#pragma unroll
        for (int p = 0; p < 4; ++p) {
            const int nrow = p * 16 + lrow;
            const float* gp = g + (size_t)(b * 64 + nrow) * CD + kc + c4;
#pragma unroll
            for (int i = 0; i < 4; ++i)
                sh.t.gt[c4 + 16 * i][nrow] = gp[16 * i];
        }
        // stage key transposed, split + dd-rotated (same element placement
        // as v1): dd = c4 + 16*i; col = ((gs+dd)&15)*4 + (srow&3)
        // write bank = 4*((gs+c4)&7) + lo -> 32 banks, 2-way (free)
#pragma unroll
        for (int p = 0; p < 8; ++p) {
            const int srow = p * 16 + lrow;
            const int gs = srow >> 3;
            const int lo = srow & 3;
            const bool hi = (srow & 4) != 0;
            const float* kp = key + (size_t)(b * SQ + s0 + srow) * CD + kc + c4;
#pragma unroll
            for (int i = 0; i < 4; ++i) {
                const int dd = c4 + 16 * i;
                const int col = (((gs + dd) & 15) << 2) + lo;
                const float vv = kp[16 * i];
                if (hi) sh.t.ktB[dd][col] = vv;
                else    sh.t.ktA[dd][col] = vv;
            }
        }
        __syncthreads();
#pragma unroll 4
        for (int dd = 0; dd < 64; ++dd) {
            const int cA = ((sg + dd) & 15) << 2;
            const float4 ga = *(const float4*)&sh.t.gt[dd][4 * ng];
            const float4 k0 = *(const float4*)&sh.t.ktA[dd][cA];
            const float4 k1 = *(const float4*)&sh.t.ktB[dd][cA];
            const float gs_[4] = { ga.x, ga.y, ga.z, ga.w };
            const float ks[8] = { k0.x, k0.y, k0.z, k0.w, k1.x, k1.y, k1.z, k1.w };
#pragma unroll
            for (int i = 0; i < 4; ++i)
#pragma unroll
                for (int j = 0; j < 8; ++j) accC[i][j] += gs_[i] * ks[j];
        }
        __syncthreads();
#pragma unroll
        for (int i = 0; i < 4; ++i)
#pragma unroll
            for (int j = 0; j < 8; ++j) { acc64[i][j] += (double)accC[i][j]; accC[i][j] = 0.f; }
    }

    double bv[8]; int bn[8];
#pragma unroll
    for (int j = 0; j < 8; ++j) {
        bv[j] = acc64[0][j] + dl[4 * ng + 0]; bn[j] = 4 * ng + 0;
#pragma unroll
        for (int i = 1; i < 4; ++i) {
            const double v = acc64[i][j] + dl[4 * ng + i];
            if (v > bv[j]) { bv[j] = v; bn[j] = 4 * ng + i; }
        }
    }
    __syncthreads();
#pragma unroll
    for (int j = 0; j < 8; ++j) {
        sh.r.bval[8 * sg + j][ng] = bv[j];
        sh.r.bidx[8 * sg + j][ng] = bn[j];
    }
    __syncthreads();
    if (tid < 128) {
        const int s = tid;
        double best = sh.r.bval[s][0]; int bi = sh.r.bidx[s][0];
        for (int k = 1; k < 16; ++k) {
            const double v = sh.r.bval[s][k];
            if (v > best) { best = v; bi = sh.r.bidx[s][k]; }
        }
        idxo[b * SQ + s0 + s] = bi;
    }
}

// ---------------------------------------------------------------------------
// gather_ksum (proven R3 kernel)
// ---------------------------------------------------------------------------
__global__ __launch_bounds__(256)
void gather_ksum(const float* __restrict__ key, const int* __restrict__ idx,
                 float* __restrict__ Ksum, int* __restrict__ cnt)
{
    __shared__ int slist[SQ];
    __shared__ int scount;
    const int n   = blockIdx.x;
    const int b   = blockIdx.y;
    const int tid = threadIdx.x;
    if (tid == 0) scount = 0;
    __syncthreads();

    const int* ib = idx + b * SQ;
#pragma unroll
    for (int p = 0; p < SQ / 256; ++p) {
        const int s = p * 256 + tid;
        if (ib[s] == n) {
            const int pos = atomicAdd(&scount, 1);
            slist[pos] = s;
        }
    }
    __syncthreads();
    const int m = scount;

    double a0 = 0.0, a1 = 0.0, a2 = 0.0;
    const float* kb = key + (size_t)b * SQ * CD;
    const int c1 = tid + 256, c2 = tid + 512;

    int r = 0;
    for (; r + 4 <= m; r += 4) {
        const float* p0 = kb + (size_t)slist[r]     * CD;
        const float* p1 = kb + (size_t)slist[r + 1] * CD;
        const float* p2 = kb + (size_t)slist[r + 2] * CD;
        const float* p3 = kb + (size_t)slist[r + 3] * CD;
        a0 += (double)p0[tid] + (double)p1[tid] + (double)p2[tid] + (double)p3[tid];
        a1 += (double)p0[c1] + (double)p1[c1] + (double)p2[c1] + (double)p3[c1];
        a2 += (double)p0[c2] + (double)p1[c2] + (double)p2[c2] + (double)p3[c2];
    }
    for (; r < m; ++r) {
        const float* p0 = kb + (size_t)slist[r] * CD;
        a0 += (double)p0[tid]; a1 += (double)p0[c1]; a2 += (double)p0[c2];
    }

    float* out = Ksum + (size_t)(b * 64 + n) * CD;
    out[tid] = (float)a0; out[c1] = (float)a1; out[c2] = (float)a2;
    if (tid == 0) cnt[b * 64 + n] = m;
}

// ---------------------------------------------------------------------------
extern "C" void kernel_launch(void* const* d_in, const int* in_sizes, int n_in,
                              void* d_out, int out_size, void* d_ws, size_t ws_size,
                              hipStream_t stream)
{
    const float* query = (const float*)d_in[0];
    const float* key   = (const float*)d_in[1];
    const float* Wq    = (const float*)d_in[2];
    const float* bq    = (const float*)d_in[3];
    const float* Wk    = (const float*)d_in[4];
    const float* bk    = (const float*)d_in[5];
    const float* Wv    = (const float*)d_in[6];
    const float* bv    = (const float*)d_in[7];
    const float* Wo    = (const float*)d_in[8];
    const float* bo    = (const float*)d_in[9];

    char* ws = (char*)d_ws;
    const size_t MB = 1 << 20;
    int*    cnt   = (int*)   (ws + 0);               //   4 KB
    double* delta = (double*)(ws + 4096);            //   8 KB
    float*  uq    = (float*) (ws + 16384);           //   3 KB
    float*  bqk   = (float*) (ws + 19456);           //   3 KB
    float*  bvo   = (float*) (ws + 22528);           //   3 KB
    int*    idx   = (int*)   (ws + 32768);           // 256 KB
    float*  qT    = (float*) (ws + 1 * MB);          //   3 MB  [768][1024]
    float*  WoT   = (float*) (ws + 4 * MB);          // 2.25 MB [768][768]
    float*  Wqk   = (float*) (ws + 7 * MB);          // 2.25 MB (contiguous with Wvo)
    float*  Wvo   = Wqk + 768 * 768;                 // 2.25 MB
    float*  g     = (float*) (ws + 12 * MB);         //   3 MB  [1024][768]
    float*  Ksum  = (float*) (ws + 15 * MB);         //   3 MB
    float*  KsumT = (float*) (ws + 18 * MB);         //   3 MB  [768][1024]
    float*  P     = (float*) (ws + 21 * MB);         //  19 MB  partials

    // weight precomputes
    transpose64<<<dim3(12, 12), 256, 0, stream>>>(Wo, WoT, CD, CD);
    transpose64<<<dim3(12, 16), 256, 0, stream>>>(query, qT, ROWS, CD);
    vecmat3<<<dim3(12, 3), 256, 0, stream>>>(Wq, bk, Wk, bq, WoT, bv, uq, bqk, bvo);
    delta_q<<<ROWS / 4, 256, 0, stream>>>(query, uq, bq, bk, delta);
    // [Wqk ; Wvo] = [Wq^T@Wk ; Wv^T@Wo^T]
    gemm_w<<<dim3(12, 24, KSP), 256, 0, stream>>>(Wq, Wk, Wv, WoT, P);
    reduce_sk<<<(1536 * CD) / 256, 256, 0, stream>>>(P, nullptr, nullptr, nullptr, Wqk, 1536, 0);
    // g = query @ Wqk + bqk
    gemm_d<<<dim3(12, 16, KSP), 256, 0, stream>>>(qT, Wqk, P);
    reduce_sk<<<(ROWS * CD) / 256, 256, 0, stream>>>(P, bqk, nullptr, nullptr, g, ROWS, 1);
    // argmax assignment (v6: v1-exact with conflict-free staging assignment)
    score_argmax<<<dim3(SQ / 128, BQ), 256, 0, stream>>>(g, key, delta, idx);
    // Ksum / cnt
    gather_ksum<<<dim3(NG, BQ), 256, 0, stream>>>(key, idx, Ksum, cnt);
    transpose64<<<dim3(12, 16), 256, 0, stream>>>(Ksum, KsumT, ROWS, CD);
    // out = invf*(Ksum @ Wvo) + bsc*bvo + bo
    gemm_d<<<dim3(12, 16, KSP), 256, 0, stream>>>(KsumT, Wvo, P);
    reduce_sk<<<(ROWS * CD) / 256, 256, 0, stream>>>(P, bo, bvo, cnt, (float*)d_out, ROWS, 3);
}

// Round 6
// 576.157 us; speedup vs baseline: 1.4000x; 1.2156x over previous
//
#include <hip/hip_runtime.h>
#include <hip/hip_bf16.h>

#define BQ 16      // batches
#define NG 64      // groups
#define SQ 4096    // sequence tokens
#define CD 768     // channels
#define ROWS (BQ*NG)
#define KSP 4      // split-K factor (768 = 4 * 192)

// ---------------------------------------------------------------------------
// transpose64: dst[N x M] = src[M x N]^T, 64x64 LDS tiles
// ---------------------------------------------------------------------------
__global__ __launch_bounds__(256)
void transpose64(const float* __restrict__ src, float* __restrict__ dst,
                 int M, int N)
{
    __shared__ float t[64][65];
    const int bx = blockIdx.x * 64;
    const int by = blockIdx.y * 64;
    const int tx = threadIdx.x & 63, tw = threadIdx.x >> 6;
#pragma unroll
    for (int i = 0; i < 16; ++i) {
        const int row = i * 4 + tw;
        t[row][tx] = src[(size_t)(by + row) * N + bx + tx];
    }
    __syncthreads();
#pragma unroll
    for (int i = 0; i < 16; ++i) {
        const int row = i * 4 + tw;
        dst[(size_t)(bx + row) * M + by + tx] = t[tx][row];
    }
}

// ---------------------------------------------------------------------------
// vecmat3: three fused vec@mat precomputes (blockIdx.y selects)
//   y=0: uq  = Wq^T bk      y=1: bqk = bq @ Wk      y=2: bvo = bv @ Wo^T
// ---------------------------------------------------------------------------
__global__ __launch_bounds__(256)
void vecmat3(const float* __restrict__ Wq, const float* __restrict__ bk,
             const float* __restrict__ Wk, const float* __restrict__ bq,
             const float* __restrict__ WoT, const float* __restrict__ bv,
             float* __restrict__ uq, float* __restrict__ bqk,
             float* __restrict__ bvo)
{
    __shared__ float red[4][64];
    const float* Mm; const float* v; float* out;
    if (blockIdx.y == 0)      { Mm = Wq;  v = bk; out = uq;  }
    else if (blockIdx.y == 1) { Mm = Wk;  v = bq; out = bqk; }
    else                      { Mm = WoT; v = bv; out = bvo; }
    const int j0 = blockIdx.x * 64;
    const int jl = threadIdx.x & 63;
    const int cs = threadIdx.x >> 6;
    double a = 0.0;
    for (int c = cs; c < CD; c += 4)
        a += (double)Mm[(size_t)c * CD + j0 + jl] * (double)v[c];
    red[cs][jl] = (float)a;
    __syncthreads();
    if (cs == 0) out[j0 + jl] = red[0][jl] + red[1][jl] + red[2][jl] + red[3][jl];
}

// ---------------------------------------------------------------------------
// delta_q: delta[r] = query[r,:].uq + bq.bk  (fp64)
// ---------------------------------------------------------------------------
__global__ __launch_bounds__(256)
void delta_q(const float* __restrict__ query, const float* __restrict__ uq,
             const float* __restrict__ bq, const float* __restrict__ bk,
             double* __restrict__ delta)
{
    const int r    = blockIdx.x * 4 + (threadIdx.x >> 6);
    const int lane = threadIdx.x & 63;
    double a = 0.0, b = 0.0;
    for (int c = lane; c < CD; c += 64) {
        a += (double)query[(size_t)r * CD + c] * (double)uq[c];
        b += (double)bq[c] * (double)bk[c];
    }
    a += b;
    for (int off = 32; off; off >>= 1) a += __shfl_down(a, off, 64);
    if (lane == 0) delta[r] = a;
}

// ---------------------------------------------------------------------------
// gemm_core: 256-thread 64x64 tile, K=192 per call (3 chunks of 64),
// 4x4 per lane. AT is A TRANSPOSED [768][lda] (staging = direct copy).
// LDS pad 72 -> all fragment reads and staging stores <=2-way (free).
// fp32 per-64-chunk partials folded into fp64 (proven score-path recipe).
// Writes fp32 partial tile into Pz (row stride CD).
// ---------------------------------------------------------------------------
__device__ __forceinline__
void gemm_core(const float* __restrict__ AT, int lda,
               const float* __restrict__ B,  int ldb,
               float* __restrict__ Pz, int r0, int c0, int k0, int prow0)
{
    __shared__ float As[64][72];
    __shared__ float Bs[64][72];
    const int tid = threadIdx.x;
    const int c4  = tid & 15;     // staging float4 col
    const int kr  = tid >> 4;     // staging row step
    const int cg  = tid & 15;     // output col group
    const int rg  = tid >> 4;     // output row group

    float  acc[4][4]; double acc64[4][4];
#pragma unroll
    for (int i = 0; i < 4; ++i)
#pragma unroll
        for (int j = 0; j < 4; ++j) { acc[i][j] = 0.f; acc64[i][j] = 0.0; }

    for (int ch = 0; ch < 3; ++ch) {
        const int kb = k0 + ch * 64;
        if (ch) __syncthreads();
#pragma unroll
        for (int i = 0; i < 4; ++i) {
            const int row = i * 16 + kr;
            *(float4*)&As[row][4 * c4] = *(const float4*)(AT + (size_t)(kb + row) * lda + r0 + 4 * c4);
            *(float4*)&Bs[row][4 * c4] = *(const float4*)(B  + (size_t)(kb + row) * ldb + c0 + 4 * c4);
        }
        __syncthreads();
#pragma unroll 8
        for (int dd = 0; dd < 64; ++dd) {
            const float4 a = *(const float4*)&As[dd][4 * rg];
            const float4 b = *(const float4*)&Bs[dd][4 * cg];
            const float av[4] = {a.x, a.y, a.z, a.w};
            const float bv[4] = {b.x, b.y, b.z, b.w};
#pragma unroll
            for (int i = 0; i < 4; ++i)
#pragma unroll
                for (int j = 0; j < 4; ++j) acc[i][j] += av[i] * bv[j];
        }
#pragma unroll
        for (int i = 0; i < 4; ++i)
#pragma unroll
            for (int j = 0; j < 4; ++j) { acc64[i][j] += (double)acc[i][j]; acc[i][j] = 0.f; }
    }
#pragma unroll
    for (int i = 0; i < 4; ++i) {
        const int row = prow0 + 4 * rg + i;
        float4 v;
        v.x = (float)acc64[i][0]; v.y = (float)acc64[i][1];
        v.z = (float)acc64[i][2]; v.w = (float)acc64[i][3];
        *(float4*)(Pz + (size_t)row * CD + c0 + 4 * cg) = v;
    }
}

// weight GEMMs fused: by<12 -> Wqk = Wq^T@Wk; by>=12 -> Wvo = Wv^T@Wo^T
__global__ __launch_bounds__(256)
void gemm_w(const float* __restrict__ Wq, const float* __restrict__ Wk,
            const float* __restrict__ Wv, const float* __restrict__ WoT,
            float* __restrict__ P)
{
    const int by = blockIdx.y;
    float* Pz = P + (size_t)blockIdx.z * (1536 * CD);
    const float* AT; const float* Bp; int r0;
    if (by < 12) { AT = Wq; Bp = Wk;  r0 = by * 64; }
    else         { AT = Wv; Bp = WoT; r0 = (by - 12) * 64; }
    gemm_core(AT, CD, Bp, CD, Pz, r0, blockIdx.x * 64, blockIdx.z * 192, by * 64);
}

// data GEMM: out-rows M=1024, AT [768][1024]
__global__ __launch_bounds__(256)
void gemm_d(const float* __restrict__ AT, const float* __restrict__ B,
            float* __restrict__ P)
{
    float* Pz = P + (size_t)blockIdx.z * (ROWS * CD);
    const int r0 = blockIdx.y * 64;
    gemm_core(AT, ROWS, B, CD, Pz, r0, blockIdx.x * 64, blockIdx.z * 192, r0);
}

// ---------------------------------------------------------------------------
// reduce_sk: out[e] = fp64 sum of KSP partials (+ epilogue).
// mode 0: none; 1: +bias[c]; 3: invf*acc + bsc*bias2[c] + bias[c]
// ---------------------------------------------------------------------------
__global__ __launch_bounds__(256)
void reduce_sk(const float* __restrict__ P, const float* __restrict__ bias,
               const float* __restrict__ bias2, const int* __restrict__ cnt,
               float* __restrict__ out, int M, int mode)
{
    const int e = blockIdx.x * 256 + threadIdx.x;
    if (e >= M * CD) return;
    const size_t MN = (size_t)M * CD;
    double a = 0.0;
#pragma unroll
    for (int z = 0; z < KSP; ++z) a += (double)P[z * MN + e];
    float v = (float)a;
    if (mode == 1) v += bias[e % CD];
    else if (mode == 3) {
        const int r = e / CD;
        const int cv = cnt[r];
        const float invf = 1.f / ((float)cv + 1.f);   // ASSIGN_EPS = 1
        v = v * invf + ((float)cv * invf) * bias2[e % CD] + bias[e % CD];
    }
    out[e] = v;
}

// ---------------------------------------------------------------------------
// score_argmax v7: EXACT v1 (proven 161us) instruction structure -- same
// float4 global staging, same scatter b32 LDS writes, same compute and
// numerics -- with ONLY the LDS placement changed:
//   * all tiles padded to stride 68
//   * k-row dd stored at LDS row sigma(dd) = ((dd&3)<<4)|(dd>>2)
// Why: v1's scatter writes had dd = 4*c4+i, so the lane-varying c4 never
// reached the bank bits (8 banks, 8-way, the 1.7e7 conflict cycles). With
// sigma the store row is 16*i + c4 and the 68-stride carries 4*c4 into the
// bank index: kt write bank = 4*((5*c4+gs+i)&7)+lo -> 32 banks / 2-way
// (free, m136); gt write bank = (4*c4+16*(p&1)+lrow)&31 -> 2-way. Reads use
// sigma(dd) too (3 cheap ops per dd, hidden); read patterns unchanged
// (2-way / broadcast). Element placement is consistent on both sides ->
// compute order, fp32 chains, fp64 folds, argmax all BIT-IDENTICAL to v1.
// ---------------------------------------------------------------------------
struct ScoreTiles { float gt[64][68]; float ktA[64][68]; float ktB[64][68]; };
struct ScoreRed   { double bval[128][17]; int bidx[128][17]; };
union  ScoreShared { ScoreTiles t; ScoreRed r; };

__global__ __launch_bounds__(256)
void score_argmax(const float* __restrict__ g, const float* __restrict__ key,
                  const double* __restrict__ delta, int* __restrict__ idxo)
{
    __shared__ alignas(16) ScoreShared sh;
    __shared__ double dl[64];
    const int tid  = threadIdx.x;
    const int b    = blockIdx.y;
    const int s0   = blockIdx.x * 128;
    const int sg   = tid & 15;    // s = 8*sg + j
    const int ng   = tid >> 4;    // n = 4*ng + i
    const int lrow = tid >> 4;
    const int c4   = tid & 15;

    if (tid < 64) dl[tid] = delta[b * 64 + tid];

    float  accC[4][8];
    double acc64[4][8];
#pragma unroll
    for (int i = 0; i < 4; ++i)
#pragma unroll
        for (int j = 0; j < 8; ++j) { accC[i][j] = 0.f; acc64[i][j] = 0.0; }

    for (int kc = 0; kc < CD; kc += 64) {
        // stage g transposed: element (k-local = 4*c4+i, n) -> row 16*i + c4
#pragma unroll
        for (int p = 0; p < 4; ++p) {
            const int nrow = p * 16 + lrow;
            const float4 v = *(const float4*)(g + (size_t)(b * 64 + nrow) * CD + kc + 4 * c4);
            sh.t.gt[c4     ][nrow] = v.x;
            sh.t.gt[c4 + 16][nrow] = v.y;
            sh.t.gt[c4 + 32][nrow] = v.z;
            sh.t.gt[c4 + 48][nrow] = v.w;
        }
        // stage key transposed, split + dd-rotated (v1 placement, sigma rows):
        //   dd = 4*c4+i -> row 16*i + c4; col = ((gs+dd)&15)*4 + (srow&3)
#pragma unroll
        for (int p = 0; p < 8; ++p) {
            const int srow = p * 16 + lrow;
            const float4 v = *(const float4*)(key + (size_t)(b * SQ + s0 + srow) * CD + kc + 4 * c4);
            const int gs = srow >> 3;
            const int lo = srow & 3;
            const bool hi = (srow & 4) != 0;
            const float vv[4] = { v.x, v.y, v.z, v.w };
#pragma unroll
            for (int i = 0; i < 4; ++i) {
                const int dd  = 4 * c4 + i;
                const int row = 16 * i + c4;          // sigma(dd)
                const int col = (((gs + dd) & 15) << 2) + lo;
                if (hi) sh.t.ktB[row][col] = vv[i];
                else    sh.t.ktA[row][col] = vv[i];
            }
        }
        __syncthreads();
#pragma unroll 4
        for (int dd = 0; dd < 64; ++dd) {
            const int sd = ((dd & 3) << 4) | (dd >> 2);   // sigma(dd)
            const int cA = ((sg + dd) & 15) << 2;
            const float4 ga = *(const float4*)&sh.t.gt[sd][4 * ng];
            const float4 k0 = *(const float4*)&sh.t.ktA[sd][cA];
            const float4 k1 = *(const float4*)&sh.t.ktB[sd][cA];
            const float gs_[4] = { ga.x, ga.y, ga.z, ga.w };
            const float ks[8] = { k0.x, k0.y, k0.z, k0.w, k1.x, k1.y, k1.z, k1.w };
#pragma unroll
            for (int i = 0; i < 4; ++i)
#pragma unroll
                for (int j = 0; j < 8; ++j) accC[i][j] += gs_[i] * ks[j];
        }
        __syncthreads();
#pragma unroll
        for (int i = 0; i < 4; ++i)
#pragma unroll
            for (int j = 0; j < 8; ++j) { acc64[i][j] += (double)accC[i][j]; accC[i][j] = 0.f; }
    }

    double bv[8]; int bn[8];
#pragma unroll
    for (int j = 0; j < 8; ++j) {
        bv[j] = acc64[0][j] + dl[4 * ng + 0]; bn[j] = 4 * ng + 0;
#pragma unroll
        for (int i = 1; i < 4; ++i) {
            const double v = acc64[i][j] + dl[4 * ng + i];
            if (v > bv[j]) { bv[j] = v; bn[j] = 4 * ng + i; }
        }
    }
    __syncthreads();
#pragma unroll
    for (int j = 0; j < 8; ++j) {
        sh.r.bval[8 * sg + j][ng] = bv[j];
        sh.r.bidx[8 * sg + j][ng] = bn[j];
    }
    __syncthreads();
    if (tid < 128) {
        const int s = tid;
        double best = sh.r.bval[s][0]; int bi = sh.r.bidx[s][0];
        for (int k = 1; k < 16; ++k) {
            const double v = sh.r.bval[s][k];
            if (v > best) { best = v; bi = sh.r.bidx[s][k]; }
        }
        idxo[b * SQ + s0 + s] = bi;
    }
}

// ---------------------------------------------------------------------------
// gather_ksum (proven R3 kernel)
// ---------------------------------------------------------------------------
__global__ __launch_bounds__(256)
void gather_ksum(const float* __restrict__ key, const int* __restrict__ idx,
                 float* __restrict__ Ksum, int* __restrict__ cnt)
{
    __shared__ int slist[SQ];
    __shared__ int scount;
    const int n   = blockIdx.x;
    const int b   = blockIdx.y;
    const int tid = threadIdx.x;
    if (tid == 0) scount = 0;
    __syncthreads();

    const int* ib = idx + b * SQ;
#pragma unroll
    for (int p = 0; p < SQ / 256; ++p) {
        const int s = p * 256 + tid;
        if (ib[s] == n) {
            const int pos = atomicAdd(&scount, 1);
            slist[pos] = s;
        }
    }
    __syncthreads();
    const int m = scount;

    double a0 = 0.0, a1 = 0.0, a2 = 0.0;
    const float* kb = key + (size_t)b * SQ * CD;
    const int c1 = tid + 256, c2 = tid + 512;

    int r = 0;
    for (; r + 4 <= m; r += 4) {
        const float* p0 = kb + (size_t)slist[r]     * CD;
        const float* p1 = kb + (size_t)slist[r + 1] * CD;
        const float* p2 = kb + (size_t)slist[r + 2] * CD;
        const float* p3 = kb + (size_t)slist[r + 3] * CD;
        a0 += (double)p0[tid] + (double)p1[tid] + (double)p2[tid] + (double)p3[tid];
        a1 += (double)p0[c1] + (double)p1[c1] + (double)p2[c1] + (double)p3[c1];
        a2 += (double)p0[c2] + (double)p1[c2] + (double)p2[c2] + (double)p3[c2];
    }
    for (; r < m; ++r) {
        const float* p0 = kb + (size_t)slist[r] * CD;
        a0 += (double)p0[tid]; a1 += (double)p0[c1]; a2 += (double)p0[c2];
    }

    float* out = Ksum + (size_t)(b * 64 + n) * CD;
    out[tid] = (float)a0; out[c1] = (float)a1; out[c2] = (float)a2;
    if (tid == 0) cnt[b * 64 + n] = m;
}

// ---------------------------------------------------------------------------
extern "C" void kernel_launch(void* const* d_in, const int* in_sizes, int n_in,
                              void* d_out, int out_size, void* d_ws, size_t ws_size,
                              hipStream_t stream)
{
    const float* query = (const float*)d_in[0];
    const float* key   = (const float*)d_in[1];
    const float* Wq    = (const float*)d_in[2];
    const float* bq    = (const float*)d_in[3];
    const float* Wk    = (const float*)d_in[4];
    const float* bk    = (const float*)d_in[5];
    const float* Wv    = (const float*)d_in[6];
    const float* bv    = (const float*)d_in[7];
    const float* Wo    = (const float*)d_in[8];
    const float* bo    = (const float*)d_in[9];

    char* ws = (char*)d_ws;
    const size_t MB = 1 << 20;
    int*    cnt   = (int*)   (ws + 0);               //   4 KB
    double* delta = (double*)(ws + 4096);            //   8 KB
    float*  uq    = (float*) (ws + 16384);           //   3 KB
    float*  bqk   = (float*) (ws + 19456);           //   3 KB
    float*  bvo   = (float*) (ws + 22528);           //   3 KB
    int*    idx   = (int*)   (ws + 32768);           // 256 KB
    float*  qT    = (float*) (ws + 1 * MB);          //   3 MB  [768][1024]
    float*  WoT   = (float*) (ws + 4 * MB);          // 2.25 MB [768][768]
    float*  Wqk   = (float*) (ws + 7 * MB);          // 2.25 MB (contiguous with Wvo)
    float*  Wvo   = Wqk + 768 * 768;                 // 2.25 MB
    float*  g     = (float*) (ws + 12 * MB);         //   3 MB  [1024][768]
    float*  Ksum  = (float*) (ws + 15 * MB);         //   3 MB
    float*  KsumT = (float*) (ws + 18 * MB);         //   3 MB  [768][1024]
    float*  P     = (float*) (ws + 21 * MB);         //  19 MB  partials

    // weight precomputes
    transpose64<<<dim3(12, 12), 256, 0, stream>>>(Wo, WoT, CD, CD);
    transpose64<<<dim3(12, 16), 256, 0, stream>>>(query, qT, ROWS, CD);
    vecmat3<<<dim3(12, 3), 256, 0, stream>>>(Wq, bk, Wk, bq, WoT, bv, uq, bqk, bvo);
    delta_q<<<ROWS / 4, 256, 0, stream>>>(query, uq, bq, bk, delta);
    // [Wqk ; Wvo] = [Wq^T@Wk ; Wv^T@Wo^T]
    gemm_w<<<dim3(12, 24, KSP), 256, 0, stream>>>(Wq, Wk, Wv, WoT, P);
    reduce_sk<<<(1536 * CD) / 256, 256, 0, stream>>>(P, nullptr, nullptr, nullptr, Wqk, 1536, 0);
    // g = query @ Wqk + bqk
    gemm_d<<<dim3(12, 16, KSP), 256, 0, stream>>>(qT, Wqk, P);
    reduce_sk<<<(ROWS * CD) / 256, 256, 0, stream>>>(P, bqk, nullptr, nullptr, g, ROWS, 1);
    // argmax assignment (v7: v1-exact with sigma-permuted conflict-free LDS)
    score_argmax<<<dim3(SQ / 128, BQ), 256, 0, stream>>>(g, key, delta, idx);
    // Ksum / cnt
    gather_ksum<<<dim3(NG, BQ), 256, 0, stream>>>(key, idx, Ksum, cnt);
    transpose64<<<dim3(12, 16), 256, 0, stream>>>(Ksum, KsumT, ROWS, CD);
    // out = invf*(Ksum @ Wvo) + bsc*bvo + bo
    gemm_d<<<dim3(12, 16, KSP), 256, 0, stream>>>(KsumT, Wvo, P);
    reduce_sk<<<(ROWS * CD) / 256, 256, 0, stream>>>(P, bo, bvo, cnt, (float*)d_out, ROWS, 3);
}

// Round 7
// 561.953 us; speedup vs baseline: 1.4353x; 1.0253x over previous
//
#include <hip/hip_runtime.h>
#include <hip/hip_bf16.h>

#define BQ 16      // batches
#define NG 64      // groups
#define SQ 4096    // sequence tokens
#define CD 768     // channels
#define ROWS (BQ*NG)
#define KSP 4      // split-K factor (768 = 4 * 192)

// ---------------------------------------------------------------------------
// transpose64: dst[N x M] = src[M x N]^T, 64x64 LDS tiles
// ---------------------------------------------------------------------------
__global__ __launch_bounds__(256)
void transpose64(const float* __restrict__ src, float* __restrict__ dst,
                 int M, int N)
{
    __shared__ float t[64][65];
    const int bx = blockIdx.x * 64;
    const int by = blockIdx.y * 64;
    const int tx = threadIdx.x & 63, tw = threadIdx.x >> 6;
#pragma unroll
    for (int i = 0; i < 16; ++i) {
        const int row = i * 4 + tw;
        t[row][tx] = src[(size_t)(by + row) * N + bx + tx];
    }
    __syncthreads();
#pragma unroll
    for (int i = 0; i < 16; ++i) {
        const int row = i * 4 + tw;
        dst[(size_t)(bx + row) * M + by + tx] = t[tx][row];
    }
}

// ---------------------------------------------------------------------------
// vecmat3: three fused vec@mat precomputes (blockIdx.y selects)
//   y=0: uq  = Wq^T bk      y=1: bqk = bq @ Wk      y=2: bvo = bv @ Wo^T
// ---------------------------------------------------------------------------
__global__ __launch_bounds__(256)
void vecmat3(const float* __restrict__ Wq, const float* __restrict__ bk,
             const float* __restrict__ Wk, const float* __restrict__ bq,
             const float* __restrict__ WoT, const float* __restrict__ bv,
             float* __restrict__ uq, float* __restrict__ bqk,
             float* __restrict__ bvo)
{
    __shared__ float red[4][64];
    const float* Mm; const float* v; float* out;
    if (blockIdx.y == 0)      { Mm = Wq;  v = bk; out = uq;  }
    else if (blockIdx.y == 1) { Mm = Wk;  v = bq; out = bqk; }
    else                      { Mm = WoT; v = bv; out = bvo; }
    const int j0 = blockIdx.x * 64;
    const int jl = threadIdx.x & 63;
    const int cs = threadIdx.x >> 6;
    double a = 0.0;
    for (int c = cs; c < CD; c += 4)
        a += (double)Mm[(size_t)c * CD + j0 + jl] * (double)v[c];
    red[cs][jl] = (float)a;
    __syncthreads();
    if (cs == 0) out[j0 + jl] = red[0][jl] + red[1][jl] + red[2][jl] + red[3][jl];
}

// ---------------------------------------------------------------------------
// delta_q: delta[r] = query[r,:].uq + bq.bk  (fp64)
// ---------------------------------------------------------------------------
__global__ __launch_bounds__(256)
void delta_q(const float* __restrict__ query, const float* __restrict__ uq,
             const float* __restrict__ bq, const float* __restrict__ bk,
             double* __restrict__ delta)
{
    const int r    = blockIdx.x * 4 + (threadIdx.x >> 6);
    const int lane = threadIdx.x & 63;
    double a = 0.0, b = 0.0;
    for (int c = lane; c < CD; c += 64) {
        a += (double)query[(size_t)r * CD + c] * (double)uq[c];
        b += (double)bq[c] * (double)bk[c];
    }
    a += b;
    for (int off = 32; off; off >>= 1) a += __shfl_down(a, off, 64);
    if (lane == 0) delta[r] = a;
}

// ---------------------------------------------------------------------------
// gemm_core: 256-thread 64x64 tile, K=192 per call (3 chunks of 64),
// 4x4 per lane. AT is A TRANSPOSED [768][lda] (staging = direct copy).
// LDS pad 72 -> all fragment reads and staging stores <=2-way (free).
// fp32 per-64-chunk partials folded into fp64 (proven score-path recipe).
// Writes fp32 partial tile into Pz (row stride CD).
// ---------------------------------------------------------------------------
__device__ __forceinline__
void gemm_core(const float* __restrict__ AT, int lda,
               const float* __restrict__ B,  int ldb,
               float* __restrict__ Pz, int r0, int c0, int k0, int prow0)
{
    __shared__ float As[64][72];
    __shared__ float Bs[64][72];
    const int tid = threadIdx.x;
    const int c4  = tid & 15;     // staging float4 col
    const int kr  = tid >> 4;     // staging row step
    const int cg  = tid & 15;     // output col group
    const int rg  = tid >> 4;     // output row group

    float  acc[4][4]; double acc64[4][4];
#pragma unroll
    for (int i = 0; i < 4; ++i)
#pragma unroll
        for (int j = 0; j < 4; ++j) { acc[i][j] = 0.f; acc64[i][j] = 0.0; }

    for (int ch = 0; ch < 3; ++ch) {
        const int kb = k0 + ch * 64;
        if (ch) __syncthreads();
#pragma unroll
        for (int i = 0; i < 4; ++i) {
            const int row = i * 16 + kr;
            *(float4*)&As[row][4 * c4] = *(const float4*)(AT + (size_t)(kb + row) * lda + r0 + 4 * c4);
            *(float4*)&Bs[row][4 * c4] = *(const float4*)(B  + (size_t)(kb + row) * ldb + c0 + 4 * c4);
        }
        __syncthreads();
#pragma unroll 8
        for (int dd = 0; dd < 64; ++dd) {
            const float4 a = *(const float4*)&As[dd][4 * rg];
            const float4 b = *(const float4*)&Bs[dd][4 * cg];
            const float av[4] = {a.x, a.y, a.z, a.w};
            const float bv[4] = {b.x, b.y, b.z, b.w};
#pragma unroll
            for (int i = 0; i < 4; ++i)
#pragma unroll
                for (int j = 0; j < 4; ++j) acc[i][j] += av[i] * bv[j];
        }
#pragma unroll
        for (int i = 0; i < 4; ++i)
#pragma unroll
            for (int j = 0; j < 4; ++j) { acc64[i][j] += (double)acc[i][j]; acc[i][j] = 0.f; }
    }
#pragma unroll
    for (int i = 0; i < 4; ++i) {
        const int row = prow0 + 4 * rg + i;
        float4 v;
        v.x = (float)acc64[i][0]; v.y = (float)acc64[i][1];
        v.z = (float)acc64[i][2]; v.w = (float)acc64[i][3];
        *(float4*)(Pz + (size_t)row * CD + c0 + 4 * cg) = v;
    }
}

// weight GEMMs fused: by<12 -> Wqk = Wq^T@Wk; by>=12 -> Wvo = Wv^T@Wo^T
__global__ __launch_bounds__(256)
void gemm_w(const float* __restrict__ Wq, const float* __restrict__ Wk,
            const float* __restrict__ Wv, const float* __restrict__ WoT,
            float* __restrict__ P)
{
    const int by = blockIdx.y;
    float* Pz = P + (size_t)blockIdx.z * (1536 * CD);
    const float* AT; const float* Bp; int r0;
    if (by < 12) { AT = Wq; Bp = Wk;  r0 = by * 64; }
    else         { AT = Wv; Bp = WoT; r0 = (by - 12) * 64; }
    gemm_core(AT, CD, Bp, CD, Pz, r0, blockIdx.x * 64, blockIdx.z * 192, by * 64);
}

// data GEMM: out-rows M=1024, AT [768][1024]
__global__ __launch_bounds__(256)
void gemm_d(const float* __restrict__ AT, const float* __restrict__ B,
            float* __restrict__ P)
{
    float* Pz = P + (size_t)blockIdx.z * (ROWS * CD);
    const int r0 = blockIdx.y * 64;
    gemm_core(AT, ROWS, B, CD, Pz, r0, blockIdx.x * 64, blockIdx.z * 192, r0);
}

// ---------------------------------------------------------------------------
// reduce_sk: out[e] = fp64 sum of KSP partials (+ epilogue).
// mode 0: none; 1: +bias[c]; 3: invf*acc + bsc*bias2[c] + bias[c]
// ---------------------------------------------------------------------------
__global__ __launch_bounds__(256)
void reduce_sk(const float* __restrict__ P, const float* __restrict__ bias,
               const float* __restrict__ bias2, const int* __restrict__ cnt,
               float* __restrict__ out, int M, int mode)
{
    const int e = blockIdx.x * 256 + threadIdx.x;
    if (e >= M * CD) return;
    const size_t MN = (size_t)M * CD;
    double a = 0.0;
#pragma unroll
    for (int z = 0; z < KSP; ++z) a += (double)P[z * MN + e];
    float v = (float)a;
    if (mode == 1) v += bias[e % CD];
    else if (mode == 3) {
        const int r = e / CD;
        const int cv = cnt[r];
        const float invf = 1.f / ((float)cv + 1.f);   // ASSIGN_EPS = 1
        v = v * invf + ((float)cv * invf) * bias2[e % CD] + bias[e % CD];
    }
    out[e] = v;
}

// ---------------------------------------------------------------------------
// score_argmax v8: v7's proven staging/sigma-layout/compute recipe with the
// s-tile HALVED (64 s per block) to double occupancy:
//   * grid (SQ/64, BQ) = 1024 blocks = 4 blocks/CU (was 2); LDS ~35 KB;
//     VGPR ~80 -> 16 waves/CU = 4 waves/SIMD (was 2). v7 proved the LDS pipe
//     has slack (removing 14M conflict cycles changed nothing) -> the wall
//     is latency/phase serialization, which TLP addresses.
//   * per-lane fragment 4n x 4s; per dd: 2 ds_read_b128 (ga broadcast + kt
//     16-distinct), 16 FMAs.
//   * kt element (dd, s) -> row sigma(dd)=16*(dd&3)+(dd>>2) wait -- row
//     ((dd&3)<<4)|(dd>>2), col ((s>>2 + dd)&15)*4 + (s&3), stride 68.
//     Staging write bank = 4*((5*c4+u)&7)+lo -> exact 2-way (free);
//     fragment read 64 distinct floats/wave -> 2-way (free).
// Numerics BIT-IDENTICAL to the proven kernel: per (s,n) one fp32 FMA per k
// ascending within each 64-chunk, fp64 fold at the same 12 boundaries, fp64
// +delta, strict-> / ascending-n argmax.
// ---------------------------------------------------------------------------
struct ScoreTiles { float gt[64][68]; float kt[64][68]; };
struct ScoreRed   { double bval[64][17]; int bidx[64][17]; };
union  ScoreShared { ScoreTiles t; ScoreRed r; };

__global__ __launch_bounds__(256)
void score_argmax(const float* __restrict__ g, const float* __restrict__ key,
                  const double* __restrict__ delta, int* __restrict__ idxo)
{
    __shared__ alignas(16) ScoreShared sh;
    __shared__ double dl[64];
    const int tid  = threadIdx.x;
    const int b    = blockIdx.y;
    const int s0   = blockIdx.x * 64;
    const int sg   = tid & 15;    // s = 4*sg + j (j=0..3)
    const int ng   = tid >> 4;    // n = 4*ng + i
    const int lrow = tid >> 4;
    const int c4   = tid & 15;

    if (tid < 64) dl[tid] = delta[b * 64 + tid];

    float  accC[4][4];
    double acc64[4][4];
#pragma unroll
    for (int i = 0; i < 4; ++i)
#pragma unroll
        for (int j = 0; j < 4; ++j) { accC[i][j] = 0.f; acc64[i][j] = 0.0; }

    for (int kc = 0; kc < CD; kc += 64) {
        // stage g transposed: element (k-local = 4*c4+i, n) -> row 16*i + c4
#pragma unroll
        for (int p = 0; p < 4; ++p) {
            const int nrow = p * 16 + lrow;
            const float4 v = *(const float4*)(g + (size_t)(b * 64 + nrow) * CD + kc + 4 * c4);
            sh.t.gt[c4     ][nrow] = v.x;
            sh.t.gt[c4 + 16][nrow] = v.y;
            sh.t.gt[c4 + 32][nrow] = v.z;
            sh.t.gt[c4 + 48][nrow] = v.w;
        }
        // stage key transposed + dd-rotated, sigma rows:
        //   dd = 4*c4+i -> row 16*i + c4; col = ((s>>2 + dd)&15)*4 + (s&3)
#pragma unroll
        for (int p = 0; p < 4; ++p) {
            const int srow = p * 16 + lrow;
            const float4 v = *(const float4*)(key + (size_t)(b * SQ + s0 + srow) * CD + kc + 4 * c4);
            const int gs = srow >> 2;
            const int lo = srow & 3;
            const float vv[4] = { v.x, v.y, v.z, v.w };
#pragma unroll
            for (int i = 0; i < 4; ++i) {
                const int dd  = 4 * c4 + i;
                const int row = 16 * i + c4;          // sigma(dd)
                const int col = (((gs + dd) & 15) << 2) + lo;
                sh.t.kt[row][col] = vv[i];
            }
        }
        __syncthreads();
#pragma unroll 4
        for (int dd = 0; dd < 64; ++dd) {
            const int sd = ((dd & 3) << 4) | (dd >> 2);   // sigma(dd)
            const float4 ga = *(const float4*)&sh.t.gt[sd][4 * ng];
            const float4 kf = *(const float4*)&sh.t.kt[sd][((sg + dd) & 15) << 2];
            const float gs_[4] = { ga.x, ga.y, ga.z, ga.w };
            const float ks[4] = { kf.x, kf.y, kf.z, kf.w };
#pragma unroll
            for (int i = 0; i < 4; ++i)
#pragma unroll
                for (int j = 0; j < 4; ++j) accC[i][j] += gs_[i] * ks[j];
        }
        __syncthreads();
#pragma unroll
        for (int i = 0; i < 4; ++i)
#pragma unroll
            for (int j = 0; j < 4; ++j) { acc64[i][j] += (double)accC[i][j]; accC[i][j] = 0.f; }
    }

    double bv[4]; int bn[4];
#pragma unroll
    for (int j = 0; j < 4; ++j) {
        bv[j] = acc64[0][j] + dl[4 * ng + 0]; bn[j] = 4 * ng + 0;
#pragma unroll
        for (int i = 1; i < 4; ++i) {
            const double v = acc64[i][j] + dl[4 * ng + i];
            if (v > bv[j]) { bv[j] = v; bn[j] = 4 * ng + i; }
        }
    }
    __syncthreads();
#pragma unroll
    for (int j = 0; j < 4; ++j) {
        sh.r.bval[4 * sg + j][ng] = bv[j];
        sh.r.bidx[4 * sg + j][ng] = bn[j];
    }
    __syncthreads();
    if (tid < 64) {
        const int s = tid;
        double best = sh.r.bval[s][0]; int bi = sh.r.bidx[s][0];
        for (int k = 1; k < 16; ++k) {
            const double v = sh.r.bval[s][k];
            if (v > best) { best = v; bi = sh.r.bidx[s][k]; }
        }
        idxo[b * SQ + s0 + s] = bi;
    }
}

// ---------------------------------------------------------------------------
// gather_ksum (proven R3 kernel)
// ---------------------------------------------------------------------------
__global__ __launch_bounds__(256)
void gather_ksum(const float* __restrict__ key, const int* __restrict__ idx,
                 float* __restrict__ Ksum, int* __restrict__ cnt)
{
    __shared__ int slist[SQ];
    __shared__ int scount;
    const int n   = blockIdx.x;
    const int b   = blockIdx.y;
    const int tid = threadIdx.x;
    if (tid == 0) scount = 0;
    __syncthreads();

    const int* ib = idx + b * SQ;
#pragma unroll
    for (int p = 0; p < SQ / 256; ++p) {
        const int s = p * 256 + tid;
        if (ib[s] == n) {
            const int pos = atomicAdd(&scount, 1);
            slist[pos] = s;
        }
    }
    __syncthreads();
    const int m = scount;

    double a0 = 0.0, a1 = 0.0, a2 = 0.0;
    const float* kb = key + (size_t)b * SQ * CD;
    const int c1 = tid + 256, c2 = tid + 512;

    int r = 0;
    for (; r + 4 <= m; r += 4) {
        const float* p0 = kb + (size_t)slist[r]     * CD;
        const float* p1 = kb + (size_t)slist[r + 1] * CD;
        const float* p2 = kb + (size_t)slist[r + 2] * CD;
        const float* p3 = kb + (size_t)slist[r + 3] * CD;
        a0 += (double)p0[tid] + (double)p1[tid] + (double)p2[tid] + (double)p3[tid];
        a1 += (double)p0[c1] + (double)p1[c1] + (double)p2[c1] + (double)p3[c1];
        a2 += (double)p0[c2] + (double)p1[c2] + (double)p2[c2] + (double)p3[c2];
    }
    for (; r < m; ++r) {
        const float* p0 = kb + (size_t)slist[r] * CD;
        a0 += (double)p0[tid]; a1 += (double)p0[c1]; a2 += (double)p0[c2];
    }

    float* out = Ksum + (size_t)(b * 64 + n) * CD;
    out[tid] = (float)a0; out[c1] = (float)a1; out[c2] = (float)a2;
    if (tid == 0) cnt[b * 64 + n] = m;
}

// ---------------------------------------------------------------------------
extern "C" void kernel_launch(void* const* d_in, const int* in_sizes, int n_in,
                              void* d_out, int out_size, void* d_ws, size_t ws_size,
                              hipStream_t stream)
{
    const float* query = (const float*)d_in[0];
    const float* key   = (const float*)d_in[1];
    const float* Wq    = (const float*)d_in[2];
    const float* bq    = (const float*)d_in[3];
    const float* Wk    = (const float*)d_in[4];
    const float* bk    = (const float*)d_in[5];
    const float* Wv    = (const float*)d_in[6];
    const float* bv    = (const float*)d_in[7];
    const float* Wo    = (const float*)d_in[8];
    const float* bo    = (const float*)d_in[9];

    char* ws = (char*)d_ws;
    const size_t MB = 1 << 20;
    int*    cnt   = (int*)   (ws + 0);               //   4 KB
    double* delta = (double*)(ws + 4096);            //   8 KB
    float*  uq    = (float*) (ws + 16384);           //   3 KB
    float*  bqk   = (float*) (ws + 19456);           //   3 KB
    float*  bvo   = (float*) (ws + 22528);           //   3 KB
    int*    idx   = (int*)   (ws + 32768);           // 256 KB
    float*  qT    = (float*) (ws + 1 * MB);          //   3 MB  [768][1024]
    float*  WoT   = (float*) (ws + 4 * MB);          // 2.25 MB [768][768]
    float*  Wqk   = (float*) (ws + 7 * MB);          // 2.25 MB (contiguous with Wvo)
    float*  Wvo   = Wqk + 768 * 768;                 // 2.25 MB
    float*  g     = (float*) (ws + 12 * MB);         //   3 MB  [1024][768]
    float*  Ksum  = (float*) (ws + 15 * MB);         //   3 MB
    float*  KsumT = (float*) (ws + 18 * MB);         //   3 MB  [768][1024]
    float*  P     = (float*) (ws + 21 * MB);         //  19 MB  partials

    // weight precomputes
    transpose64<<<dim3(12, 12), 256, 0, stream>>>(Wo, WoT, CD, CD);
    transpose64<<<dim3(12, 16), 256, 0, stream>>>(query, qT, ROWS, CD);
    vecmat3<<<dim3(12, 3), 256, 0, stream>>>(Wq, bk, Wk, bq, WoT, bv, uq, bqk, bvo);
    delta_q<<<ROWS / 4, 256, 0, stream>>>(query, uq, bq, bk, delta);
    // [Wqk ; Wvo] = [Wq^T@Wk ; Wv^T@Wo^T]
    gemm_w<<<dim3(12, 24, KSP), 256, 0, stream>>>(Wq, Wk, Wv, WoT, P);
    reduce_sk<<<(1536 * CD) / 256, 256, 0, stream>>>(P, nullptr, nullptr, nullptr, Wqk, 1536, 0);
    // g = query @ Wqk + bqk
    gemm_d<<<dim3(12, 16, KSP), 256, 0, stream>>>(qT, Wqk, P);
    reduce_sk<<<(ROWS * CD) / 256, 256, 0, stream>>>(P, bqk, nullptr, nullptr, g, ROWS, 1);
    // argmax assignment (v8: 64-s tile, 4 blocks/CU for latency hiding)
    score_argmax<<<dim3(SQ / 64, BQ), 256, 0, stream>>>(g, key, delta, idx);
    // Ksum / cnt
    gather_ksum<<<dim3(NG, BQ), 256, 0, stream>>>(key, idx, Ksum, cnt);
    transpose64<<<dim3(12, 16), 256, 0, stream>>>(Ksum, KsumT, ROWS, CD);
    // out = invf*(Ksum @ Wvo) + bsc*bvo + bo
    gemm_d<<<dim3(12, 16, KSP), 256, 0, stream>>>(KsumT, Wvo, P);
    reduce_sk<<<(ROWS * CD) / 256, 256, 0, stream>>>(P, bo, bvo, cnt, (float*)d_out, ROWS, 3);
}

// Round 8
// 547.524 us; speedup vs baseline: 1.4732x; 1.0264x over previous
//
#include <hip/hip_runtime.h>
#include <hip/hip_bf16.h>

#define BQ 16      // batches
#define NG 64      // groups
#define SQ 4096    // sequence tokens
#define CD 768     // channels
#define ROWS (BQ*NG)
#define KSP 4      // split-K factor (768 = 4 * 192)

// ---------------------------------------------------------------------------
// transpose64: dst[N x M] = src[M x N]^T, 64x64 LDS tiles
// ---------------------------------------------------------------------------
__global__ __launch_bounds__(256)
void transpose64(const float* __restrict__ src, float* __restrict__ dst,
                 int M, int N)
{
    __shared__ float t[64][65];
    const int bx = blockIdx.x * 64;
    const int by = blockIdx.y * 64;
    const int tx = threadIdx.x & 63, tw = threadIdx.x >> 6;
#pragma unroll
    for (int i = 0; i < 16; ++i) {
        const int row = i * 4 + tw;
        t[row][tx] = src[(size_t)(by + row) * N + bx + tx];
    }
    __syncthreads();
#pragma unroll
    for (int i = 0; i < 16; ++i) {
        const int row = i * 4 + tw;
        dst[(size_t)(bx + row) * M + by + tx] = t[tx][row];
    }
}

// ---------------------------------------------------------------------------
// vecmat3: three fused vec@mat precomputes (blockIdx.y selects)
//   y=0: uq  = Wq^T bk      y=1: bqk = bq @ Wk      y=2: bvo = bv @ Wo^T
// ---------------------------------------------------------------------------
__global__ __launch_bounds__(256)
void vecmat3(const float* __restrict__ Wq, const float* __restrict__ bk,
             const float* __restrict__ Wk, const float* __restrict__ bq,
             const float* __restrict__ WoT, const float* __restrict__ bv,
             float* __restrict__ uq, float* __restrict__ bqk,
             float* __restrict__ bvo)
{
    __shared__ float red[4][64];
    const float* Mm; const float* v; float* out;
    if (blockIdx.y == 0)      { Mm = Wq;  v = bk; out = uq;  }
    else if (blockIdx.y == 1) { Mm = Wk;  v = bq; out = bqk; }
    else                      { Mm = WoT; v = bv; out = bvo; }
    const int j0 = blockIdx.x * 64;
    const int jl = threadIdx.x & 63;
    const int cs = threadIdx.x >> 6;
    double a = 0.0;
    for (int c = cs; c < CD; c += 4)
        a += (double)Mm[(size_t)c * CD + j0 + jl] * (double)v[c];
    red[cs][jl] = (float)a;
    __syncthreads();
    if (cs == 0) out[j0 + jl] = red[0][jl] + red[1][jl] + red[2][jl] + red[3][jl];
}

// ---------------------------------------------------------------------------
// delta_q: delta[r] = query[r,:].uq + bq.bk  (fp64)
// ---------------------------------------------------------------------------
__global__ __launch_bounds__(256)
void delta_q(const float* __restrict__ query, const float* __restrict__ uq,
             const float* __restrict__ bq, const float* __restrict__ bk,
             double* __restrict__ delta)
{
    const int r    = blockIdx.x * 4 + (threadIdx.x >> 6);
    const int lane = threadIdx.x & 63;
    double a = 0.0, b = 0.0;
    for (int c = lane; c < CD; c += 64) {
        a += (double)query[(size_t)r * CD + c] * (double)uq[c];
        b += (double)bq[c] * (double)bk[c];
    }
    a += b;
    for (int off = 32; off; off >>= 1) a += __shfl_down(a, off, 64);
    if (lane == 0) delta[r] = a;
}

// ---------------------------------------------------------------------------
// gemm_core: 256-thread 64x64 tile, K=192 per call (3 chunks of 64),
// 4x4 per lane. AT is A TRANSPOSED [768][lda] (staging = direct copy).
// LDS pad 72 -> all fragment reads and staging stores <=2-way (free).
// fp32 per-64-chunk partials folded into fp64 (proven score-path recipe).
// Writes fp32 partial tile into Pz (row stride CD).
// ---------------------------------------------------------------------------
__device__ __forceinline__
void gemm_core(const float* __restrict__ AT, int lda,
               const float* __restrict__ B,  int ldb,
               float* __restrict__ Pz, int r0, int c0, int k0, int prow0)
{
    __shared__ float As[64][72];
    __shared__ float Bs[64][72];
    const int tid = threadIdx.x;
    const int c4  = tid & 15;     // staging float4 col
    const int kr  = tid >> 4;     // staging row step
    const int cg  = tid & 15;     // output col group
    const int rg  = tid >> 4;     // output row group

    float  acc[4][4]; double acc64[4][4];
#pragma unroll
    for (int i = 0; i < 4; ++i)
#pragma unroll
        for (int j = 0; j < 4; ++j) { acc[i][j] = 0.f; acc64[i][j] = 0.0; }

    for (int ch = 0; ch < 3; ++ch) {
        const int kb = k0 + ch * 64;
        if (ch) __syncthreads();
#pragma unroll
        for (int i = 0; i < 4; ++i) {
            const int row = i * 16 + kr;
            *(float4*)&As[row][4 * c4] = *(const float4*)(AT + (size_t)(kb + row) * lda + r0 + 4 * c4);
            *(float4*)&Bs[row][4 * c4] = *(const float4*)(B  + (size_t)(kb + row) * ldb + c0 + 4 * c4);
        }
        __syncthreads();
#pragma unroll 8
        for (int dd = 0; dd < 64; ++dd) {
            const float4 a = *(const float4*)&As[dd][4 * rg];
            const float4 b = *(const float4*)&Bs[dd][4 * cg];
            const float av[4] = {a.x, a.y, a.z, a.w};
            const float bv[4] = {b.x, b.y, b.z, b.w};
#pragma unroll
            for (int i = 0; i < 4; ++i)
#pragma unroll
                for (int j = 0; j < 4; ++j) acc[i][j] += av[i] * bv[j];
        }
#pragma unroll
        for (int i = 0; i < 4; ++i)
#pragma unroll
            for (int j = 0; j < 4; ++j) { acc64[i][j] += (double)acc[i][j]; acc[i][j] = 0.f; }
    }
#pragma unroll
    for (int i = 0; i < 4; ++i) {
        const int row = prow0 + 4 * rg + i;
        float4 v;
        v.x = (float)acc64[i][0]; v.y = (float)acc64[i][1];
        v.z = (float)acc64[i][2]; v.w = (float)acc64[i][3];
        *(float4*)(Pz + (size_t)row * CD + c0 + 4 * cg) = v;
    }
}

// weight GEMMs fused: by<12 -> Wqk = Wq^T@Wk; by>=12 -> Wvo = Wv^T@Wo^T
__global__ __launch_bounds__(256)
void gemm_w(const float* __restrict__ Wq, const float* __restrict__ Wk,
            const float* __restrict__ Wv, const float* __restrict__ WoT,
            float* __restrict__ P)
{
    const int by = blockIdx.y;
    float* Pz = P + (size_t)blockIdx.z * (1536 * CD);
    const float* AT; const float* Bp; int r0;
    if (by < 12) { AT = Wq; Bp = Wk;  r0 = by * 64; }
    else         { AT = Wv; Bp = WoT; r0 = (by - 12) * 64; }
    gemm_core(AT, CD, Bp, CD, Pz, r0, blockIdx.x * 64, blockIdx.z * 192, by * 64);
}

// data GEMM: out-rows M=1024, AT [768][1024]
__global__ __launch_bounds__(256)
void gemm_d(const float* __restrict__ AT, const float* __restrict__ B,
            float* __restrict__ P)
{
    float* Pz = P + (size_t)blockIdx.z * (ROWS * CD);
    const int r0 = blockIdx.y * 64;
    gemm_core(AT, ROWS, B, CD, Pz, r0, blockIdx.x * 64, blockIdx.z * 192, r0);
}

// ---------------------------------------------------------------------------
// reduce_sk: out[e] = fp64 sum of KSP partials (+ epilogue).
// mode 0: none; 1: +bias[c]; 3: invf*acc + bsc*bias2[c] + bias[c]
// ---------------------------------------------------------------------------
__global__ __launch_bounds__(256)
void reduce_sk(const float* __restrict__ P, const float* __restrict__ bias,
               const float* __restrict__ bias2, const int* __restrict__ cnt,
               float* __restrict__ out, int M, int mode)
{
    const int e = blockIdx.x * 256 + threadIdx.x;
    if (e >= M * CD) return;
    const size_t MN = (size_t)M * CD;
    double a = 0.0;
#pragma unroll
    for (int z = 0; z < KSP; ++z) a += (double)P[z * MN + e];
    float v = (float)a;
    if (mode == 1) v += bias[e % CD];
    else if (mode == 3) {
        const int r = e / CD;
        const int cv = cnt[r];
        const float invf = 1.f / ((float)cv + 1.f);   // ASSIGN_EPS = 1
        v = v * invf + ((float)cv * invf) * bias2[e % CD] + bias[e % CD];
    }
    out[e] = v;
}

// ---------------------------------------------------------------------------
// score_argmax v9: v8 (139.5us) + two numerics-identical edits:
//   (1) T14 async-stage: chunk t+1 loaded into 8 transient float4 regs
//       between the post-stage barrier and compute of chunk t; written to
//       LDS after the next barrier. HBM latency hides under ~2000 cyc of
//       FMA instead of stalling the stage phase 12x per block.
//       Register budget ~100 < 128 -> __launch_bounds__(256,4), no spill
//       (verify: WRITE_SIZE stays ~256 KB).
//   (2) kt column rotation removed (dead weight from v1's layout): col = s.
//       With sigma rows, staging write bank = (4*c4+16p+lrow)&31 -> exact
//       2-way (free); fragment read = 16 distinct float4 -> 2-way (free).
//       Saves 2 VALU ops per dd.
// Element placement consistent on write & read; load timing changes only ->
// fp32 chains, fp64 folds, argmax BIT-IDENTICAL to the proven kernel.
// ---------------------------------------------------------------------------
struct ScoreTiles { float gt[64][68]; float kt[64][68]; };
struct ScoreRed   { double bval[64][17]; int bidx[64][17]; };
union  ScoreShared { ScoreTiles t; ScoreRed r; };

__global__ __launch_bounds__(256, 4)
void score_argmax(const float* __restrict__ g, const float* __restrict__ key,
                  const double* __restrict__ delta, int* __restrict__ idxo)
{
    __shared__ alignas(16) ScoreShared sh;
    __shared__ double dl[64];
    const int tid  = threadIdx.x;
    const int b    = blockIdx.y;
    const int s0   = blockIdx.x * 64;
    const int sg   = tid & 15;    // s = 4*sg + j (j=0..3)
    const int ng   = tid >> 4;    // n = 4*ng + i
    const int lrow = tid >> 4;
    const int c4   = tid & 15;

    if (tid < 64) dl[tid] = delta[b * 64 + tid];

    float  accC[4][4];
    double acc64[4][4];
#pragma unroll
    for (int i = 0; i < 4; ++i)
#pragma unroll
        for (int j = 0; j < 4; ++j) { accC[i][j] = 0.f; acc64[i][j] = 0.0; }

    const float* gb = g   + (size_t)(b * 64) * CD;
    const float* kb = key + (size_t)(b * SQ + s0) * CD;

    // prologue: chunk 0 -> registers
    float4 rg_[4], rk[4];
#pragma unroll
    for (int p = 0; p < 4; ++p) {
        const int row = p * 16 + lrow;
        rg_[p] = *(const float4*)(gb + (size_t)row * CD + 4 * c4);
        rk[p]  = *(const float4*)(kb + (size_t)row * CD + 4 * c4);
    }

    for (int t = 0; t < 12; ++t) {
        __syncthreads();              // previous compute done -> LDS writable
        // ---- write staged regs to LDS (sigma rows, col = n / s directly)
#pragma unroll
        for (int p = 0; p < 4; ++p) {
            const int nrow = p * 16 + lrow;
            sh.t.gt[c4     ][nrow] = rg_[p].x;
            sh.t.gt[c4 + 16][nrow] = rg_[p].y;
            sh.t.gt[c4 + 32][nrow] = rg_[p].z;
            sh.t.gt[c4 + 48][nrow] = rg_[p].w;
        }
#pragma unroll
        for (int p = 0; p < 4; ++p) {
            const int srow = p * 16 + lrow;
            sh.t.kt[c4     ][srow] = rk[p].x;
            sh.t.kt[c4 + 16][srow] = rk[p].y;
            sh.t.kt[c4 + 32][srow] = rk[p].z;
            sh.t.kt[c4 + 48][srow] = rk[p].w;
        }
        __syncthreads();              // LDS ready
        // ---- prefetch chunk t+1 into regs (latency hides under compute)
        if (t < 11) {
            const int kc = (t + 1) * 64;
#pragma unroll
            for (int p = 0; p < 4; ++p) {
                const int row = p * 16 + lrow;
                rg_[p] = *(const float4*)(gb + (size_t)row * CD + kc + 4 * c4);
                rk[p]  = *(const float4*)(kb + (size_t)row * CD + kc + 4 * c4);
            }
        }
        // ---- compute chunk t: dd ascending 0..63 (sigma row lookup)
#pragma unroll 4
        for (int dd = 0; dd < 64; ++dd) {
            const int sd = ((dd & 3) << 4) | (dd >> 2);   // sigma(dd)
            const float4 ga = *(const float4*)&sh.t.gt[sd][4 * ng];
            const float4 kf = *(const float4*)&sh.t.kt[sd][4 * sg];
            const float gs_[4] = { ga.x, ga.y, ga.z, ga.w };
            const float ks[4] = { kf.x, kf.y, kf.z, kf.w };
#pragma unroll
            for (int i = 0; i < 4; ++i)
#pragma unroll
                for (int j = 0; j < 4; ++j) accC[i][j] += gs_[i] * ks[j];
        }
        // ---- fold fp32 chunk partial into fp64 (same 12 boundaries)
#pragma unroll
        for (int i = 0; i < 4; ++i)
#pragma unroll
            for (int j = 0; j < 4; ++j) { acc64[i][j] += (double)accC[i][j]; accC[i][j] = 0.f; }
    }

    double bv[4]; int bn[4];
#pragma unroll
    for (int j = 0; j < 4; ++j) {
        bv[j] = acc64[0][j] + dl[4 * ng + 0]; bn[j] = 4 * ng + 0;
#pragma unroll
        for (int i = 1; i < 4; ++i) {
            const double v = acc64[i][j] + dl[4 * ng + i];
            if (v > bv[j]) { bv[j] = v; bn[j] = 4 * ng + i; }
        }
    }
    __syncthreads();
#pragma unroll
    for (int j = 0; j < 4; ++j) {
        sh.r.bval[4 * sg + j][ng] = bv[j];
        sh.r.bidx[4 * sg + j][ng] = bn[j];
    }
    __syncthreads();
    if (tid < 64) {
        const int s = tid;
        double best = sh.r.bval[s][0]; int bi = sh.r.bidx[s][0];
        for (int k = 1; k < 16; ++k) {
            const double v = sh.r.bval[s][k];
            if (v > best) { best = v; bi = sh.r.bidx[s][k]; }
        }
        idxo[b * SQ + s0 + s] = bi;
    }
}

// ---------------------------------------------------------------------------
// gather_ksum (proven R3 kernel)
// ---------------------------------------------------------------------------
__global__ __launch_bounds__(256)
void gather_ksum(const float* __restrict__ key, const int* __restrict__ idx,
                 float* __restrict__ Ksum, int* __restrict__ cnt)
{
    __shared__ int slist[SQ];
    __shared__ int scount;
    const int n   = blockIdx.x;
    const int b   = blockIdx.y;
    const int tid = threadIdx.x;
    if (tid == 0) scount = 0;
    __syncthreads();

    const int* ib = idx + b * SQ;
#pragma unroll
    for (int p = 0; p < SQ / 256; ++p) {
        const int s = p * 256 + tid;
        if (ib[s] == n) {
            const int pos = atomicAdd(&scount, 1);
            slist[pos] = s;
        }
    }
    __syncthreads();
    const int m = scount;

    double a0 = 0.0, a1 = 0.0, a2 = 0.0;
    const float* kb = key + (size_t)b * SQ * CD;
    const int c1 = tid + 256, c2 = tid + 512;

    int r = 0;
    for (; r + 4 <= m; r += 4) {
        const float* p0 = kb + (size_t)slist[r]     * CD;
        const float* p1 = kb + (size_t)slist[r + 1] * CD;
        const float* p2 = kb + (size_t)slist[r + 2] * CD;
        const float* p3 = kb + (size_t)slist[r + 3] * CD;
        a0 += (double)p0[tid] + (double)p1[tid] + (double)p2[tid] + (double)p3[tid];
        a1 += (double)p0[c1] + (double)p1[c1] + (double)p2[c1] + (double)p3[c1];
        a2 += (double)p0[c2] + (double)p1[c2] + (double)p2[c2] + (double)p3[c2];
    }
    for (; r < m; ++r) {
        const float* p0 = kb + (size_t)slist[r] * CD;
        a0 += (double)p0[tid]; a1 += (double)p0[c1]; a2 += (double)p0[c2];
    }

    float* out = Ksum + (size_t)(b * 64 + n) * CD;
    out[tid] = (float)a0; out[c1] = (float)a1; out[c2] = (float)a2;
    if (tid == 0) cnt[b * 64 + n] = m;
}

// ---------------------------------------------------------------------------
extern "C" void kernel_launch(void* const* d_in, const int* in_sizes, int n_in,
                              void* d_out, int out_size, void* d_ws, size_t ws_size,
                              hipStream_t stream)
{
    const float* query = (const float*)d_in[0];
    const float* key   = (const float*)d_in[1];
    const float* Wq    = (const float*)d_in[2];
    const float* bq    = (const float*)d_in[3];
    const float* Wk    = (const float*)d_in[4];
    const float* bk    = (const float*)d_in[5];
    const float* Wv    = (const float*)d_in[6];
    const float* bv    = (const float*)d_in[7];
    const float* Wo    = (const float*)d_in[8];
    const float* bo    = (const float*)d_in[9];

    char* ws = (char*)d_ws;
    const size_t MB = 1 << 20;
    int*    cnt   = (int*)   (ws + 0);               //   4 KB
    double* delta = (double*)(ws + 4096);            //   8 KB
    float*  uq    = (float*) (ws + 16384);           //   3 KB
    float*  bqk   = (float*) (ws + 19456);           //   3 KB
    float*  bvo   = (float*) (ws + 22528);           //   3 KB
    int*    idx   = (int*)   (ws + 32768);           // 256 KB
    float*  qT    = (float*) (ws + 1 * MB);          //   3 MB  [768][1024]
    float*  WoT   = (float*) (ws + 4 * MB);          // 2.25 MB [768][768]
    float*  Wqk   = (float*) (ws + 7 * MB);          // 2.25 MB (contiguous with Wvo)
    float*  Wvo   = Wqk + 768 * 768;                 // 2.25 MB
    float*  g     = (float*) (ws + 12 * MB);         //   3 MB  [1024][768]
    float*  Ksum  = (float*) (ws + 15 * MB);         //   3 MB
    float*  KsumT = (float*) (ws + 18 * MB);         //   3 MB  [768][1024]
    float*  P     = (float*) (ws + 21 * MB);         //  19 MB  partials

    // weight precomputes
    transpose64<<<dim3(12, 12), 256, 0, stream>>>(Wo, WoT, CD, CD);
    transpose64<<<dim3(12, 16), 256, 0, stream>>>(query, qT, ROWS, CD);
    vecmat3<<<dim3(12, 3), 256, 0, stream>>>(Wq, bk, Wk, bq, WoT, bv, uq, bqk, bvo);
    delta_q<<<ROWS / 4, 256, 0, stream>>>(query, uq, bq, bk, delta);
    // [Wqk ; Wvo] = [Wq^T@Wk ; Wv^T@Wo^T]
    gemm_w<<<dim3(12, 24, KSP), 256, 0, stream>>>(Wq, Wk, Wv, WoT, P);
    reduce_sk<<<(1536 * CD) / 256, 256, 0, stream>>>(P, nullptr, nullptr, nullptr, Wqk, 1536, 0);
    // g = query @ Wqk + bqk
    gemm_d<<<dim3(12, 16, KSP), 256, 0, stream>>>(qT, Wqk, P);
    reduce_sk<<<(ROWS * CD) / 256, 256, 0, stream>>>(P, bqk, nullptr, nullptr, g, ROWS, 1);
    // argmax assignment (v9: v8 + async-stage prefetch + rotation removed)
    score_argmax<<<dim3(SQ / 64, BQ), 256, 0, stream>>>(g, key, delta, idx);
    // Ksum / cnt
    gather_ksum<<<dim3(NG, BQ), 256, 0, stream>>>(key, idx, Ksum, cnt);
    transpose64<<<dim3(12, 16), 256, 0, stream>>>(Ksum, KsumT, ROWS, CD);
    // out = invf*(Ksum @ Wvo) + bsc*bvo + bo
    gemm_d<<<dim3(12, 16, KSP), 256, 0, stream>>>(KsumT, Wvo, P);
    reduce_sk<<<(ROWS * CD) / 256, 256, 0, stream>>>(P, bo, bvo, cnt, (float*)d_out, ROWS, 3);
}

// Round 9
// 535.498 us; speedup vs baseline: 1.5063x; 1.0225x over previous
//
#include <hip/hip_runtime.h>
#include <hip/hip_bf16.h>

#define BQ 16      // batches
#define NG 64      // groups
#define SQ 4096    // sequence tokens
#define CD 768     // channels
#define ROWS (BQ*NG)
#define KSP 4      // split-K factor (768 = 4 * 192)

// ---------------------------------------------------------------------------
// transpose64: dst[N x M] = src[M x N]^T, 64x64 LDS tiles
// ---------------------------------------------------------------------------
__global__ __launch_bounds__(256)
void transpose64(const float* __restrict__ src, float* __restrict__ dst,
                 int M, int N)
{
    __shared__ float t[64][65];
    const int bx = blockIdx.x * 64;
    const int by = blockIdx.y * 64;
    const int tx = threadIdx.x & 63, tw = threadIdx.x >> 6;
#pragma unroll
    for (int i = 0; i < 16; ++i) {
        const int row = i * 4 + tw;
        t[row][tx] = src[(size_t)(by + row) * N + bx + tx];
    }
    __syncthreads();
#pragma unroll
    for (int i = 0; i < 16; ++i) {
        const int row = i * 4 + tw;
        dst[(size_t)(bx + row) * M + by + tx] = t[tx][row];
    }
}

// ---------------------------------------------------------------------------
// vecmat3: three fused vec@mat precomputes (blockIdx.y selects)
//   y=0: uq  = Wq^T bk      y=1: bqk = bq @ Wk      y=2: bvo = bv @ Wo^T
// ---------------------------------------------------------------------------
__global__ __launch_bounds__(256)
void vecmat3(const float* __restrict__ Wq, const float* __restrict__ bk,
             const float* __restrict__ Wk, const float* __restrict__ bq,
             const float* __restrict__ WoT, const float* __restrict__ bv,
             float* __restrict__ uq, float* __restrict__ bqk,
             float* __restrict__ bvo)
{
    __shared__ float red[4][64];
    const float* Mm; const float* v; float* out;
    if (blockIdx.y == 0)      { Mm = Wq;  v = bk; out = uq;  }
    else if (blockIdx.y == 1) { Mm = Wk;  v = bq; out = bqk; }
    else                      { Mm = WoT; v = bv; out = bvo; }
    const int j0 = blockIdx.x * 64;
    const int jl = threadIdx.x & 63;
    const int cs = threadIdx.x >> 6;
    double a = 0.0;
    for (int c = cs; c < CD; c += 4)
        a += (double)Mm[(size_t)c * CD + j0 + jl] * (double)v[c];
    red[cs][jl] = (float)a;
    __syncthreads();
    if (cs == 0) out[j0 + jl] = red[0][jl] + red[1][jl] + red[2][jl] + red[3][jl];
}

// ---------------------------------------------------------------------------
// delta_q: delta[r] = query[r,:].uq + bq.bk  (fp64)
// ---------------------------------------------------------------------------
__global__ __launch_bounds__(256)
void delta_q(const float* __restrict__ query, const float* __restrict__ uq,
             const float* __restrict__ bq, const float* __restrict__ bk,
             double* __restrict__ delta)
{
    const int r    = blockIdx.x * 4 + (threadIdx.x >> 6);
    const int lane = threadIdx.x & 63;
    double a = 0.0, b = 0.0;
    for (int c = lane; c < CD; c += 64) {
        a += (double)query[(size_t)r * CD + c] * (double)uq[c];
        b += (double)bq[c] * (double)bk[c];
    }
    a += b;
    for (int off = 32; off; off >>= 1) a += __shfl_down(a, off, 64);
    if (lane == 0) delta[r] = a;
}

// ---------------------------------------------------------------------------
// gemm_core: 256-thread 64x64 tile, K=192 per call (3 chunks of 64),
// 4x4 per lane. AT is A TRANSPOSED [768][lda] (staging = direct copy).
// LDS pad 72 -> all fragment reads and staging stores <=2-way (free).
// fp32 per-64-chunk partials folded into fp64 (proven score-path recipe).
// Writes fp32 partial tile into Pz (row stride CD).
// ---------------------------------------------------------------------------
__device__ __forceinline__
void gemm_core(const float* __restrict__ AT, int lda,
               const float* __restrict__ B,  int ldb,
               float* __restrict__ Pz, int r0, int c0, int k0, int prow0)
{
    __shared__ float As[64][72];
    __shared__ float Bs[64][72];
    const int tid = threadIdx.x;
    const int c4  = tid & 15;     // staging float4 col
    const int kr  = tid >> 4;     // staging row step
    const int cg  = tid & 15;     // output col group
    const int rg  = tid >> 4;     // output row group

    float  acc[4][4]; double acc64[4][4];
#pragma unroll
    for (int i = 0; i < 4; ++i)
#pragma unroll
        for (int j = 0; j < 4; ++j) { acc[i][j] = 0.f; acc64[i][j] = 0.0; }

    for (int ch = 0; ch < 3; ++ch) {
        const int kb = k0 + ch * 64;
        if (ch) __syncthreads();
#pragma unroll
        for (int i = 0; i < 4; ++i) {
            const int row = i * 16 + kr;
            *(float4*)&As[row][4 * c4] = *(const float4*)(AT + (size_t)(kb + row) * lda + r0 + 4 * c4);
            *(float4*)&Bs[row][4 * c4] = *(const float4*)(B  + (size_t)(kb + row) * ldb + c0 + 4 * c4);
        }
        __syncthreads();
#pragma unroll 8
        for (int dd = 0; dd < 64; ++dd) {
            const float4 a = *(const float4*)&As[dd][4 * rg];
            const float4 b = *(const float4*)&Bs[dd][4 * cg];
            const float av[4] = {a.x, a.y, a.z, a.w};
            const float bv[4] = {b.x, b.y, b.z, b.w};
#pragma unroll
            for (int i = 0; i < 4; ++i)
#pragma unroll
                for (int j = 0; j < 4; ++j) acc[i][j] += av[i] * bv[j];
        }
#pragma unroll
        for (int i = 0; i < 4; ++i)
#pragma unroll
            for (int j = 0; j < 4; ++j) { acc64[i][j] += (double)acc[i][j]; acc[i][j] = 0.f; }
    }
#pragma unroll
    for (int i = 0; i < 4; ++i) {
        const int row = prow0 + 4 * rg + i;
        float4 v;
        v.x = (float)acc64[i][0]; v.y = (float)acc64[i][1];
        v.z = (float)acc64[i][2]; v.w = (float)acc64[i][3];
        *(float4*)(Pz + (size_t)row * CD + c0 + 4 * cg) = v;
    }
}

// weight GEMMs fused: by<12 -> Wqk = Wq^T@Wk; by>=12 -> Wvo = Wv^T@Wo^T
__global__ __launch_bounds__(256)
void gemm_w(const float* __restrict__ Wq, const float* __restrict__ Wk,
            const float* __restrict__ Wv, const float* __restrict__ WoT,
            float* __restrict__ P)
{
    const int by = blockIdx.y;
    float* Pz = P + (size_t)blockIdx.z * (1536 * CD);
    const float* AT; const float* Bp; int r0;
    if (by < 12) { AT = Wq; Bp = Wk;  r0 = by * 64; }
    else         { AT = Wv; Bp = WoT; r0 = (by - 12) * 64; }
    gemm_core(AT, CD, Bp, CD, Pz, r0, blockIdx.x * 64, blockIdx.z * 192, by * 64);
}

// data GEMM: out-rows M=1024, AT [768][1024]
__global__ __launch_bounds__(256)
void gemm_d(const float* __restrict__ AT, const float* __restrict__ B,
            float* __restrict__ P)
{
    float* Pz = P + (size_t)blockIdx.z * (ROWS * CD);
    const int r0 = blockIdx.y * 64;
    gemm_core(AT, ROWS, B, CD, Pz, r0, blockIdx.x * 64, blockIdx.z * 192, r0);
}

// ---------------------------------------------------------------------------
// reduce_sk: out[e] = fp64 sum of KSP partials (+ epilogue).
// mode 0: none; 1: +bias[c]; 3: invf*acc + bsc*bias2[c] + bias[c]
// ---------------------------------------------------------------------------
__global__ __launch_bounds__(256)
void reduce_sk(const float* __restrict__ P, const float* __restrict__ bias,
               const float* __restrict__ bias2, const int* __restrict__ cnt,
               float* __restrict__ out, int M, int mode)
{
    const int e = blockIdx.x * 256 + threadIdx.x;
    if (e >= M * CD) return;
    const size_t MN = (size_t)M * CD;
    double a = 0.0;
#pragma unroll
    for (int z = 0; z < KSP; ++z) a += (double)P[z * MN + e];
    float v = (float)a;
    if (mode == 1) v += bias[e % CD];
    else if (mode == 3) {
        const int r = e / CD;
        const int cv = cnt[r];
        const float invf = 1.f / ((float)cv + 1.f);   // ASSIGN_EPS = 1
        v = v * invf + ((float)cv * invf) * bias2[e % CD] + bias[e % CD];
    }
    out[e] = v;
}

// ---------------------------------------------------------------------------
// score_argmax v10: v9's sigma-layout + async-stage recipe, fragment grown
// to 4n x 8s on a 128-s tile to cut LDS instructions per FMA (v9 is
// LDS-instruction-bound: 2 reads/16 FMA -> measured 120us == byte model).
//   * 128s x 64n tile, 256 thr, grid (32,16) = 512 = 2 blocks/CU.
//   * per dd: 1 ga (broadcast) + 2 kf b128 = 3 reads feeding 32 FMAs
//     (ratio 0.75 vs v9's 1.0) -> model: 4.7M LDS instrs -> ~77us + staging.
//   * kt[64][132]: stride 132 -> staging write bank (4*c4+16p+lrow)%32 =
//     2-way (free); kf read 16 distinct b128 -> 2/bank (free); gt as v9.
//   * async-stage: 12 float4 prefetch regs (48 VGPR); accumulator 96 VGPR
//     (4x8 fp32+fp64) -> ~165 total < 256 cap (launch_bounds(256,2));
//     NO spill expected (verify WRITE_SIZE ~256 KB; v2/v3 failed at 192-reg
//     8x8 accumulator, this is not that).
// Numerics BIT-IDENTICAL: ascending-dd fp32 chains per 64-chunk, fp64 fold
// at the same 12 boundaries, fp64 +delta, strict-> / ascending-n argmax.
// ---------------------------------------------------------------------------
struct ScoreTiles { float gt[64][68]; float kt[64][132]; };
struct ScoreRed   { double bval[128][17]; int bidx[128][17]; };
union  ScoreShared { ScoreTiles t; ScoreRed r; };

__global__ __launch_bounds__(256, 2)
void score_argmax(const float* __restrict__ g, const float* __restrict__ key,
                  const double* __restrict__ delta, int* __restrict__ idxo)
{
    __shared__ alignas(16) ScoreShared sh;
    __shared__ double dl[64];
    const int tid = threadIdx.x;
    const int b   = blockIdx.y;
    const int s0  = blockIdx.x * 128;
    const int sg  = tid & 15;     // s = 8*sg + j (j=0..7)
    const int ng  = tid >> 4;     // n = 4*ng + i
    const int t4  = tid >> 4;     // staging row sub-index (0..15)
    const int c4  = tid & 15;     // staging float4 col

    if (tid < 64) dl[tid] = delta[b * 64 + tid];

    float  accC[4][8];
    double acc64[4][8];
#pragma unroll
    for (int i = 0; i < 4; ++i)
#pragma unroll
        for (int j = 0; j < 8; ++j) { accC[i][j] = 0.f; acc64[i][j] = 0.0; }

    const float* gb = g   + (size_t)(b * 64) * CD;
    const float* kb = key + (size_t)(b * SQ + s0) * CD;

    // prologue: chunk 0 -> registers (4 g rows + 8 key rows per thread)
    float4 rg_[4], rk[8];
#pragma unroll
    for (int p = 0; p < 4; ++p)
        rg_[p] = *(const float4*)(gb + (size_t)(p * 16 + t4) * CD + 4 * c4);
#pragma unroll
    for (int p = 0; p < 8; ++p)
        rk[p] = *(const float4*)(kb + (size_t)(p * 16 + t4) * CD + 4 * c4);

    for (int t = 0; t < 12; ++t) {
        __syncthreads();              // previous compute done -> LDS writable
        // ---- write staged regs to LDS (sigma rows: dd=4*c4+i -> 16*i+c4)
#pragma unroll
        for (int p = 0; p < 4; ++p) {
            const int nrow = p * 16 + t4;
            sh.t.gt[c4     ][nrow] = rg_[p].x;
            sh.t.gt[c4 + 16][nrow] = rg_[p].y;
            sh.t.gt[c4 + 32][nrow] = rg_[p].z;
            sh.t.gt[c4 + 48][nrow] = rg_[p].w;
        }
#pragma unroll
        for (int p = 0; p < 8; ++p) {
            const int srow = p * 16 + t4;
            sh.t.kt[c4     ][srow] = rk[p].x;
            sh.t.kt[c4 + 16][srow] = rk[p].y;
            sh.t.kt[c4 + 32][srow] = rk[p].z;
            sh.t.kt[c4 + 48][srow] = rk[p].w;
        }
        __syncthreads();              // LDS ready
        // ---- prefetch chunk t+1 into regs (hides under compute)
        if (t < 11) {
            const int kc = (t + 1) * 64;
#pragma unroll
            for (int p = 0; p < 4; ++p)
                rg_[p] = *(const float4*)(gb + (size_t)(p * 16 + t4) * CD + kc + 4 * c4);
#pragma unroll
            for (int p = 0; p < 8; ++p)
                rk[p] = *(const float4*)(kb + (size_t)(p * 16 + t4) * CD + kc + 4 * c4);
        }
        // ---- compute chunk t: dd ascending 0..63 (sigma row lookup)
#pragma unroll 4
        for (int dd = 0; dd < 64; ++dd) {
            const int sd = ((dd & 3) << 4) | (dd >> 2);   // sigma(dd)
            const float4 ga = *(const float4*)&sh.t.gt[sd][4 * ng];
            const float4 k0 = *(const float4*)&sh.t.kt[sd][8 * sg];
            const float4 k1 = *(const float4*)&sh.t.kt[sd][8 * sg + 4];
            const float gs_[4] = { ga.x, ga.y, ga.z, ga.w };
            const float ks[8] = { k0.x, k0.y, k0.z, k0.w, k1.x, k1.y, k1.z, k1.w };
#pragma unroll
            for (int i = 0; i < 4; ++i)
#pragma unroll
                for (int j = 0; j < 8; ++j) accC[i][j] += gs_[i] * ks[j];
        }
        // ---- fold fp32 chunk partial into fp64 (same 12 boundaries)
#pragma unroll
        for (int i = 0; i < 4; ++i)
#pragma unroll
            for (int j = 0; j < 8; ++j) { acc64[i][j] += (double)accC[i][j]; accC[i][j] = 0.f; }
    }

    double bv[8]; int bn[8];
#pragma unroll
    for (int j = 0; j < 8; ++j) {
        bv[j] = acc64[0][j] + dl[4 * ng + 0]; bn[j] = 4 * ng + 0;
#pragma unroll
        for (int i = 1; i < 4; ++i) {
            const double v = acc64[i][j] + dl[4 * ng + i];
            if (v > bv[j]) { bv[j] = v; bn[j] = 4 * ng + i; }
        }
    }
    __syncthreads();
#pragma unroll
    for (int j = 0; j < 8; ++j) {
        sh.r.bval[8 * sg + j][ng] = bv[j];
        sh.r.bidx[8 * sg + j][ng] = bn[j];
    }
    __syncthreads();
    if (tid < 128) {
        const int s = tid;
        double best = sh.r.bval[s][0]; int bi = sh.r.bidx[s][0];
        for (int k = 1; k < 16; ++k) {
            const double v = sh.r.bval[s][k];
            if (v > best) { best = v; bi = sh.r.bidx[s][k]; }
        }
        idxo[b * SQ + s0 + s] = bi;
    }
}

// ---------------------------------------------------------------------------
// gather_ksum (proven R3 kernel)
// ---------------------------------------------------------------------------
__global__ __launch_bounds__(256)
void gather_ksum(const float* __restrict__ key, const int* __restrict__ idx,
                 float* __restrict__ Ksum, int* __restrict__ cnt)
{
    __shared__ int slist[SQ];
    __shared__ int scount;
    const int n   = blockIdx.x;
    const int b   = blockIdx.y;
    const int tid = threadIdx.x;
    if (tid == 0) scount = 0;
    __syncthreads();

    const int* ib = idx + b * SQ;
#pragma unroll
    for (int p = 0; p < SQ / 256; ++p) {
        const int s = p * 256 + tid;
        if (ib[s] == n) {
            const int pos = atomicAdd(&scount, 1);
            slist[pos] = s;
        }
    }
    __syncthreads();
    const int m = scount;

    double a0 = 0.0, a1 = 0.0, a2 = 0.0;
    const float* kb = key + (size_t)b * SQ * CD;
    const int c1 = tid + 256, c2 = tid + 512;

    int r = 0;
    for (; r + 4 <= m; r += 4) {
        const float* p0 = kb + (size_t)slist[r]     * CD;
        const float* p1 = kb + (size_t)slist[r + 1] * CD;
        const float* p2 = kb + (size_t)slist[r + 2] * CD;
        const float* p3 = kb + (size_t)slist[r + 3] * CD;
        a0 += (double)p0[tid] + (double)p1[tid] + (double)p2[tid] + (double)p3[tid];
        a1 += (double)p0[c1] + (double)p1[c1] + (double)p2[c1] + (double)p3[c1];
        a2 += (double)p0[c2] + (double)p1[c2] + (double)p2[c2] + (double)p3[c2];
    }
    for (; r < m; ++r) {
        const float* p0 = kb + (size_t)slist[r] * CD;
        a0 += (double)p0[tid]; a1 += (double)p0[c1]; a2 += (double)p0[c2];
    }

    float* out = Ksum + (size_t)(b * 64 + n) * CD;
    out[tid] = (float)a0; out[c1] = (float)a1; out[c2] = (float)a2;
    if (tid == 0) cnt[b * 64 + n] = m;
}

// ---------------------------------------------------------------------------
extern "C" void kernel_launch(void* const* d_in, const int* in_sizes, int n_in,
                              void* d_out, int out_size, void* d_ws, size_t ws_size,
                              hipStream_t stream)
{
    const float* query = (const float*)d_in[0];
    const float* key   = (const float*)d_in[1];
    const float* Wq    = (const float*)d_in[2];
    const float* bq    = (const float*)d_in[3];
    const float* Wk    = (const float*)d_in[4];
    const float* bk    = (const float*)d_in[5];
    const float* Wv    = (const float*)d_in[6];
    const float* bv    = (const float*)d_in[7];
    const float* Wo    = (const float*)d_in[8];
    const float* bo    = (const float*)d_in[9];

    char* ws = (char*)d_ws;
    const size_t MB = 1 << 20;
    int*    cnt   = (int*)   (ws + 0);               //   4 KB
    double* delta = (double*)(ws + 4096);            //   8 KB
    float*  uq    = (float*) (ws + 16384);           //   3 KB
    float*  bqk   = (float*) (ws + 19456);           //   3 KB
    float*  bvo   = (float*) (ws + 22528);           //   3 KB
    int*    idx   = (int*)   (ws + 32768);           // 256 KB
    float*  qT    = (float*) (ws + 1 * MB);          //   3 MB  [768][1024]
    float*  WoT   = (float*) (ws + 4 * MB);          // 2.25 MB [768][768]
    float*  Wqk   = (float*) (ws + 7 * MB);          // 2.25 MB (contiguous with Wvo)
    float*  Wvo   = Wqk + 768 * 768;                 // 2.25 MB
    float*  g     = (float*) (ws + 12 * MB);         //   3 MB  [1024][768]
    float*  Ksum  = (float*) (ws + 15 * MB);         //   3 MB
    float*  KsumT = (float*) (ws + 18 * MB);         //   3 MB  [768][1024]
    float*  P     = (float*) (ws + 21 * MB);         //  19 MB  partials

    // weight precomputes
    transpose64<<<dim3(12, 12), 256, 0, stream>>>(Wo, WoT, CD, CD);
    transpose64<<<dim3(12, 16), 256, 0, stream>>>(query, qT, ROWS, CD);
    vecmat3<<<dim3(12, 3), 256, 0, stream>>>(Wq, bk, Wk, bq, WoT, bv, uq, bqk, bvo);
    delta_q<<<ROWS / 4, 256, 0, stream>>>(query, uq, bq, bk, delta);
    // [Wqk ; Wvo] = [Wq^T@Wk ; Wv^T@Wo^T]
    gemm_w<<<dim3(12, 24, KSP), 256, 0, stream>>>(Wq, Wk, Wv, WoT, P);
    reduce_sk<<<(1536 * CD) / 256, 256, 0, stream>>>(P, nullptr, nullptr, nullptr, Wqk, 1536, 0);
    // g = query @ Wqk + bqk
    gemm_d<<<dim3(12, 16, KSP), 256, 0, stream>>>(qT, Wqk, P);
    reduce_sk<<<(ROWS * CD) / 256, 256, 0, stream>>>(P, bqk, nullptr, nullptr, g, ROWS, 1);
    // argmax assignment (v10: 128-s tile, 4x8 frags, sigma layout, prefetch)
    score_argmax<<<dim3(SQ / 128, BQ), 256, 0, stream>>>(g, key, delta, idx);
    // Ksum / cnt
    gather_ksum<<<dim3(NG, BQ), 256, 0, stream>>>(key, idx, Ksum, cnt);
    transpose64<<<dim3(12, 16), 256, 0, stream>>>(Ksum, KsumT, ROWS, CD);
    // out = invf*(Ksum @ Wvo) + bsc*bvo + bo
    gemm_d<<<dim3(12, 16, KSP), 256, 0, stream>>>(KsumT, Wvo, P);
    reduce_sk<<<(ROWS * CD) / 256, 256, 0, stream>>>(P, bo, bvo, cnt, (float*)d_out, ROWS, 3);
}